// Round 15
// baseline (896.244 us; speedup 1.0000x reference)
//
#include <hip/hip_runtime.h>
#include <hip/hip_bf16.h>
#include <cstdint>
#include <cstddef>

#define SEQ_LEN 1024
#define NBATCH  2
#define MROWS   2048          // NBATCH*SEQ_LEN, row index m = b*SEQ_LEN + s
#define DMODEL  768
#define DINNER  1536
#define DTRANK  48
#define DSTATE  16
#define NLAYERS 4
#define NVOCAB  32000
#define XPROJ_N 80            // DTRANK + 2*DSTATE
#define NCHUNK  16
#define CHUNK   64            // SEQ_LEN / NCHUNK
#define GROUPS  (NBATCH * DINNER)          // 3072
#define SCANW   (GROUPS * DSTATE)          // 49152
#define XSPLIT  8             // xproj split-K factor
#define WSPLIT  4             // W_out split-K factor

typedef __attribute__((ext_vector_type(4))) float f32x4;
typedef __attribute__((ext_vector_type(8))) short s16x8;
using bf16 = __hip_bfloat16;

__device__ __forceinline__ float b2f(bf16 v){ return __bfloat162float(v); }
__device__ __forceinline__ bf16  f2b(float v){ return __float2bfloat16(v); }
__device__ __forceinline__ short f2bs(float v){
  return (short)__builtin_bit_cast(unsigned short, __float2bfloat16(v));
}
__device__ __forceinline__ float us2f(ushort u){
  return __bfloat162float(__builtin_bit_cast(bf16, u));
}

// async global->LDS, 16B per lane; LDS dest = (wave-uniform base) + lane*16
__device__ __forceinline__ void glds16(const ushort* g, ushort* l) {
  __builtin_amdgcn_global_load_lds(
      (const __attribute__((address_space(1))) void*)g,
      (__attribute__((address_space(3))) void*)l,
      16, 0, 0);
}

// ---------------- merged f32 -> bf16 convert for all 5 weight tensors ----------------
#define CVT_E0 6144000            // emb     24,576,000 elems /4
#define CVT_E1 (CVT_E0 + 2359296) // + W_in   9,437,184 /4
#define CVT_E2 (CVT_E1 + 1179648) // + W_out  4,718,592 /4
#define CVT_E3 (CVT_E2 + 122880)  // + W_xproj  491,520 /4
#define CVT_E4 (CVT_E3 + 73728)   // + W_dt     294,912 /4
__global__ __launch_bounds__(256) void k_cvt5(
    const float* __restrict__ s0, const float* __restrict__ s1,
    const float* __restrict__ s2, const float* __restrict__ s3,
    const float* __restrict__ s4,
    ushort* __restrict__ d0, ushort* __restrict__ d1,
    ushort* __restrict__ d2, ushort* __restrict__ d3,
    ushort* __restrict__ d4)
{
  int i = blockIdx.x * 256 + threadIdx.x;
  const float* s; ushort* d; int base;
  if      (i < CVT_E0) { s = s0; d = d0; base = 0; }
  else if (i < CVT_E1) { s = s1; d = d1; base = CVT_E0; }
  else if (i < CVT_E2) { s = s2; d = d2; base = CVT_E1; }
  else if (i < CVT_E3) { s = s3; d = d3; base = CVT_E2; }
  else if (i < CVT_E4) { s = s4; d = d4; base = CVT_E3; }
  else return;
  int li = i - base;
  f32x4 v = *(const f32x4*)(s + (size_t)li * 4);
  ushort4 o;
  o.x = (ushort)f2bs(v[0]); o.y = (ushort)f2bs(v[1]);
  o.z = (ushort)f2bs(v[2]); o.w = (ushort)f2bs(v[3]);
  *(ushort4*)(d + (size_t)li * 4) = o;
}

// ---------------- sum XSPLIT f32 partials -> bf16 (xproj split-K reduce) ----------------
__global__ __launch_bounds__(256) void k_xsum(const float* __restrict__ p,
    ushort* __restrict__ out, int n4) {
  int i = blockIdx.x * 256 + threadIdx.x;
  if (i >= n4) return;
  f32x4 s = {};
#pragma unroll
  for (int z = 0; z < XSPLIT; z++) {
    f32x4 v = *(const f32x4*)(p + (size_t)z * (MROWS * XPROJ_N) + (size_t)i * 4);
    s[0] += v[0]; s[1] += v[1]; s[2] += v[2]; s[3] += v[3];
  }
  ushort4 o;
  o.x = (ushort)f2bs(s[0]); o.y = (ushort)f2bs(s[1]);
  o.z = (ushort)f2bs(s[2]); o.w = (ushort)f2bs(s[3]);
  *(ushort4*)(out + (size_t)i * 4) = o;
}

// ---------------- LN body shared by k_embed_ln / k_lnadd ----------------
__device__ __forceinline__ void ln_rows(const float v0[3], int t,
    const float* __restrict__ g, const float* __restrict__ b,
    bf16* __restrict__ outrow) {
  float s = 0.f, s2 = 0.f;
#pragma unroll
  for (int j = 0; j < 3; j++) { s += v0[j]; s2 += v0[j] * v0[j]; }
#pragma unroll
  for (int o = 32; o >= 1; o >>= 1) { s += __shfl_xor(s, o); s2 += __shfl_xor(s2, o); }
  __shared__ float red[8];
  int wave = t >> 6;
  if ((t & 63) == 0) { red[wave] = s; red[4 + wave] = s2; }
  __syncthreads();
  s  = red[0] + red[1] + red[2] + red[3];
  s2 = red[4] + red[5] + red[6] + red[7];
  float mean = s * (1.f / DMODEL);
  float var  = s2 * (1.f / DMODEL) - mean * mean;
  float rstd = rsqrtf(var + 1e-5f);
#pragma unroll
  for (int j = 0; j < 3; j++) {
    int d = t + j * 256;
    outrow[d] = f2b((v0[j] - mean) * rstd * g[d] + b[d]);
  }
}

// ---------------- fused embedding gather + layer-0 LN ----------------
__global__ __launch_bounds__(256) void k_embed_ln(const int* __restrict__ tok,
    const float* __restrict__ emb, float* __restrict__ x,
    bf16* __restrict__ out, const float* __restrict__ g, const float* __restrict__ b) {
  int m = blockIdx.x;
  const float* row = emb + (size_t)tok[m] * DMODEL;
  int t = threadIdx.x;
  float v0[3];
#pragma unroll
  for (int j = 0; j < 3; j++) {
    v0[j] = row[t + j * 256];
    x[(size_t)m * DMODEL + t + j * 256] = v0[j];   // residual base
  }
  ln_rows(v0, t, g, b, out + (size_t)m * DMODEL);
}

// ---------------- residual-add (4 W_out split-K partials) + LayerNorm ----------------
__global__ __launch_bounds__(256) void k_lnadd(float* __restrict__ x,
    const float* __restrict__ part, bf16* __restrict__ out,
    const float* __restrict__ g, const float* __restrict__ b) {
  int m = blockIdx.x;
  int t = threadIdx.x;
  float v0[3];
#pragma unroll
  for (int j = 0; j < 3; j++) {
    int d = t + j * 256;
    size_t idx = (size_t)m * DMODEL + d;
    float v = x[idx];
#pragma unroll
    for (int z = 0; z < WSPLIT; z++) v += part[(size_t)z * (MROWS * DMODEL) + idx];
    x[idx] = v;
    v0[j] = v;
  }
  ln_rows(v0, t, g, b, out + (size_t)m * DMODEL);
}

// ---------------- 128x128 GEMM, 8 waves (W_in / W_out) ----------------
// OMODE: 0 f32, 2 bf16, 3 f32 partial at slice blockIdx.z (stride MROWS*DMODEL).
template<bool HAS_BIAS, int OMODE>
__global__ __launch_bounds__(512, 4) void k_gemm128(
    const ushort* __restrict__ A, int lda,
    const ushort* __restrict__ B, int ldb,
    void* __restrict__ C, int ldc,
    const float* __restrict__ bias,
    int M, int N, int K)
{
  __shared__ ushort As[2][128 * 32];
  __shared__ ushort Bs[2][128 * 32];
  const int t = threadIdx.x;             // 0..511
  const int lane = t & 63;
  const int wave = t >> 6;               // 0..7
  const int tile_m = blockIdx.x * 128;
  const int tile_n = blockIdx.y * 128;
  const int kper = K / gridDim.z;
  const int kb = blockIdx.z * kper;
  const int ke = kb + kper;
  const int wr = (wave >> 1) * 32;       // 4 M-groups of 32
  const int wc = (wave & 1) * 64;        // 2 N-groups of 64

  f32x4 acc[2][4] = {};

  const int sr = wave * 16 + (lane >> 2);
  const int sc = (lane & 3) * 8;
  const ushort* gA = A + (size_t)(tile_m + sr) * lda + sc + kb;
  const ushort* gB = B + (size_t)(tile_n + sr) * ldb + sc + kb;

  const int fr = lane & 15;
  const int kk = (lane >> 4) * 8;

  auto stage = [&](int bb) {
    glds16(gA, &As[bb][wave * 512]);
    glds16(gB, &Bs[bb][wave * 512]);
    gA += 32; gB += 32;
  };

  stage(0);
  int cur = 0;

  for (int k0 = kb; k0 < ke; k0 += 32) {
    if (k0 + 32 < ke) {
      stage(cur ^ 1);                                   // prefetch next tile
      asm volatile("s_waitcnt vmcnt(2)" ::: "memory");  // drain current tile only
    } else {
      asm volatile("s_waitcnt vmcnt(0)" ::: "memory");
    }
    __builtin_amdgcn_s_barrier();

    s16x8 a[2], b[4];
#pragma unroll
    for (int m = 0; m < 2; m++)
      a[m] = *(const s16x8*)&As[cur][(wr + m * 16 + fr) * 32 + kk];
#pragma unroll
    for (int n = 0; n < 4; n++)
      b[n] = *(const s16x8*)&Bs[cur][(wc + n * 16 + fr) * 32 + kk];
#pragma unroll
    for (int m = 0; m < 2; m++)
#pragma unroll
      for (int n = 0; n < 4; n++)
        acc[m][n] = __builtin_amdgcn_mfma_f32_16x16x32_bf16(a[m], b[n], acc[m][n], 0, 0, 0);

    __builtin_amdgcn_s_barrier();
    cur ^= 1;
  }

  const int rq = (lane >> 4) * 4;
#pragma unroll
  for (int m = 0; m < 2; m++)
#pragma unroll
    for (int n = 0; n < 4; n++) {
      int colg = tile_n + wc + n * 16 + fr;
      float bv = HAS_BIAS ? bias[colg] : 0.f;
#pragma unroll
      for (int r = 0; r < 4; r++) {
        int rowg = tile_m + wr + m * 16 + rq + r;
        size_t idx = (size_t)rowg * ldc + colg;
        float v = acc[m][n][r] + bv;
        if constexpr (OMODE == 0) ((float*)C)[idx] = v;
        else if constexpr (OMODE == 2) ((bf16*)C)[idx] = f2b(v);
        else ((float*)C)[(size_t)blockIdx.z * (MROWS * DMODEL) + idx] = v;
      }
    }
}

// ---------------- head GEMM: 256x256, 4-phase/K-tile deep pipeline (T2+T3+T4+T5) ----------------
// 512 thr, 8 waves (2Mx4N), wave = 128x64 (acc 8x4). BK=64, NT=K/64=12.
// LDS 128KB: As/Bs[2 dbuf][2 half: 128 rows][128B rows], wave wm reads A-half wm,
// wave wn reads B-half wn>>1. Phases (16 MFMA each, setprio-wrapped):
//  ph1: rd a_lo(mf0-3)+b_lo(nf0-1) | stage A(t+1)H1 | MFMA lo x lo
//  ph2: rd b_hi(nf2-3)             | stage B(t+1)H0 | MFMA lo x hi
//  ph3: rd a_hi(mf4-7)             | stage B(t+1)H1 | MFMA hi x hi
//  ph4: rd b_lo again              | stage A(t+2)H0 | vmcnt | MFMA hi x lo
// WAR-safe: every stage target's prior reads end >= one barrier before issue
// (A-reads end ph3, B-reads end ph4; cross-buffer targets ended last K-tile).
// vmcnt ledger (2 loads/half-tile/wave): prologue 5 half-tiles -> vmcnt(2);
// steady vmcnt(2) at ph4 drains exactly K-tile t+1's 4 halves, leaves
// A(t+2)H0 in flight (never 0 mid-loop); vmcnt(0) only at t=NT-2.
// Swizzle (verified r11/r12, 0 conflicts): source chunk = (l&7)^(l>>3) during
// staging (linear LDS dest); read chunk = (ks*4+(lane>>4)) ^ (fr&7).
template<bool HAS_BIAS>
__global__ __launch_bounds__(512, 2) void k_gemmhead(
    const ushort* __restrict__ A, int lda,
    const ushort* __restrict__ B, int ldb,
    float* __restrict__ C, int ldc,
    const float* __restrict__ bias,
    int M, int N, int K)
{
  __shared__ ushort As[2][2][128 * 64];  // [dbuf][half][rows*64] = 64KB
  __shared__ ushort Bs[2][2][128 * 64];  // 64KB
  const int t = threadIdx.x;             // 0..511
  const int lane = t & 63;
  const int wave = t >> 6;               // 0..7
  const int tile_m = blockIdx.x * 256;
  const int tile_n = blockIdx.y * 256;
  const int wm = wave >> 2;              // 0..1: rows wm*128..+127 (A-half wm)
  const int wn = wave & 3;               // 0..3: cols wn*64..+63 (B-half wn>>1)
  const int bh = wn >> 1;
  const int fr = lane & 15;
  const int f7 = fr & 7;
  const int kq = lane >> 4;              // 0..3

  f32x4 acc[8][4] = {};

  // staging geometry: per glds16 (one 64-row group), lane l -> row l>>3,
  // slot l&7 (linear LDS); source chunk pre-swizzled (l&7)^(l>>3).
  const int srow = wave * 8 + (lane >> 3);             // 0..63 within group
  const int schk = ((lane & 7) ^ (lane >> 3)) * 8;     // swizzled src chunk (ushorts)

  // stage one half-tile (128 rows) of A or B at K-offset kt*64: 2 glds16
  auto stageA = [&](int d, int h, int kt) {
#pragma unroll
    for (int j = 0; j < 2; j++)
      glds16(A + (size_t)(tile_m + h * 128 + j * 64 + srow) * lda + kt * 64 + schk,
             &As[d][h][(j * 64 + wave * 8) * 64]);
  };
  auto stageB = [&](int d, int h, int kt) {
#pragma unroll
    for (int j = 0; j < 2; j++)
      glds16(B + (size_t)(tile_n + h * 128 + j * 64 + srow) * ldb + kt * 64 + schk,
             &Bs[d][h][(j * 64 + wave * 8) * 64]);
  };

  const int NT = K / 64;                 // 12

  // prologue: K-tile0 (4 halves) + A(1)H0 = 10 loads; drain to 2 = tile0 landed
  stageA(0, 0, 0); stageA(0, 1, 0);
  stageB(0, 0, 0); stageB(0, 1, 0);
  stageA(1, 0, 1);
  asm volatile("s_waitcnt vmcnt(2)" ::: "memory");
  __builtin_amdgcn_s_barrier();

  s16x8 a[4][2], b[2][2];
  // swizzled read: ushort offset = localrow*64 + ((ks*4+kq)^(localrow&7))*8
  auto rdA = [&](int d, int mfl, int hi4, int ks) {  // local row = (hi4+mfl)*16+fr
    int lr = (hi4 + mfl) * 16 + fr;
    return *(const s16x8*)&As[d][wm][lr * 64 + (((ks * 4 + kq) ^ f7) * 8)];
  };
  auto rdB = [&](int d, int nfl, int hi2, int ks) {  // local row = (wn&1)*64+(hi2+nfl)*16+fr
    int lr = (wn & 1) * 64 + (hi2 + nfl) * 16 + fr;
    return *(const s16x8*)&Bs[d][bh][lr * 64 + (((ks * 4 + kq) ^ f7) * 8)];
  };

  for (int tt = 0; tt < NT; ++tt) {
    const int d  = tt & 1;
    const int dn = d ^ 1;

    // ---- phase 1: a_lo + b_lo; stage A(t+1)H1; MFMA lo x lo
#pragma unroll
    for (int mf = 0; mf < 4; mf++)
#pragma unroll
      for (int ks = 0; ks < 2; ks++) a[mf][ks] = rdA(d, mf, 0, ks);
#pragma unroll
    for (int nf = 0; nf < 2; nf++)
#pragma unroll
      for (int ks = 0; ks < 2; ks++) b[nf][ks] = rdB(d, nf, 0, ks);
    if (tt + 1 < NT) stageA(dn, 1, tt + 1);
    __builtin_amdgcn_s_barrier();
    __builtin_amdgcn_s_setprio(1);
#pragma unroll
    for (int mf = 0; mf < 4; mf++)
#pragma unroll
      for (int nf = 0; nf < 2; nf++)
#pragma unroll
        for (int ks = 0; ks < 2; ks++)
          acc[mf][nf] = __builtin_amdgcn_mfma_f32_16x16x32_bf16(a[mf][ks], b[nf][ks], acc[mf][nf], 0, 0, 0);
    __builtin_amdgcn_s_setprio(0);
    __builtin_amdgcn_s_barrier();

    // ---- phase 2: b_hi; stage B(t+1)H0; MFMA lo x hi
#pragma unroll
    for (int nf = 0; nf < 2; nf++)
#pragma unroll
      for (int ks = 0; ks < 2; ks++) b[nf][ks] = rdB(d, nf, 2, ks);
    if (tt + 1 < NT) stageB(dn, 0, tt + 1);
    __builtin_amdgcn_s_barrier();
    __builtin_amdgcn_s_setprio(1);
#pragma unroll
    for (int mf = 0; mf < 4; mf++)
#pragma unroll
      for (int nf = 0; nf < 2; nf++)
#pragma unroll
        for (int ks = 0; ks < 2; ks++)
          acc[mf][nf + 2] = __builtin_amdgcn_mfma_f32_16x16x32_bf16(a[mf][ks], b[nf][ks], acc[mf][nf + 2], 0, 0, 0);
    __builtin_amdgcn_s_setprio(0);
    __builtin_amdgcn_s_barrier();

    // ---- phase 3: a_hi; stage B(t+1)H1; MFMA hi x hi
#pragma unroll
    for (int mf = 0; mf < 4; mf++)
#pragma unroll
      for (int ks = 0; ks < 2; ks++) a[mf][ks] = rdA(d, mf, 4, ks);
    if (tt + 1 < NT) stageB(dn, 1, tt + 1);
    __builtin_amdgcn_s_barrier();
    __builtin_amdgcn_s_setprio(1);
#pragma unroll
    for (int mf = 0; mf < 4; mf++)
#pragma unroll
      for (int nf = 0; nf < 2; nf++)
#pragma unroll
        for (int ks = 0; ks < 2; ks++)
          acc[mf + 4][nf + 2] = __builtin_amdgcn_mfma_f32_16x16x32_bf16(a[mf][ks], b[nf][ks], acc[mf + 4][nf + 2], 0, 0, 0);
    __builtin_amdgcn_s_setprio(0);
    __builtin_amdgcn_s_barrier();

    // ---- phase 4: b_lo again; stage A(t+2)H0; vmcnt; MFMA hi x lo
#pragma unroll
    for (int nf = 0; nf < 2; nf++)
#pragma unroll
      for (int ks = 0; ks < 2; ks++) b[nf][ks] = rdB(d, nf, 0, ks);
    if (tt + 2 < NT) {
      stageA(d, 0, tt + 2);
      asm volatile("s_waitcnt vmcnt(2)" ::: "memory");   // K-tile t+1 landed
    } else if (tt + 1 < NT) {
      asm volatile("s_waitcnt vmcnt(0)" ::: "memory");   // final prefetch drain
    }
    __builtin_amdgcn_s_barrier();
    __builtin_amdgcn_s_setprio(1);
#pragma unroll
    for (int mf = 0; mf < 4; mf++)
#pragma unroll
      for (int nf = 0; nf < 2; nf++)
#pragma unroll
        for (int ks = 0; ks < 2; ks++)
          acc[mf + 4][nf] = __builtin_amdgcn_mfma_f32_16x16x32_bf16(a[mf][ks], b[nf][ks], acc[mf + 4][nf], 0, 0, 0);
    __builtin_amdgcn_s_setprio(0);
    __builtin_amdgcn_s_barrier();
  }

  const int rq = (lane >> 4) * 4;
#pragma unroll
  for (int mf = 0; mf < 8; mf++)
#pragma unroll
    for (int nf = 0; nf < 4; nf++) {
      int colg = tile_n + wn * 64 + nf * 16 + fr;
      float bv = HAS_BIAS ? bias[colg] : 0.f;
#pragma unroll
      for (int r = 0; r < 4; r++) {
        int rowg = tile_m + wm * 128 + mf * 16 + rq + r;
        C[(size_t)rowg * ldc + colg] = acc[mf][nf][r] + bv;
      }
    }
}

// ---------------- small GEMM (bounds-checked 64x64): C = A * W^T, bf16 inputs ----------------
// MODE: 0 = bf16 out
//       2 = dt-fused: sp=softplus(acc+bias[col]) -> dtf[idx]=sp (f32),
//           dtx[idx]=bf16(sp*xcb[idx])
//       3 = f32 partial out at slice blockIdx.z (xproj split-K; stride MROWS*XPROJ_N)
template<int MODE>
__global__ __launch_bounds__(256) void k_gemm(
    const ushort* __restrict__ A, int lda,
    const ushort* __restrict__ W, int ldw,
    void* __restrict__ Cout, int ldc,
    int M, int N, int K,
    const float* __restrict__ bias,
    const bf16* __restrict__ xcb,
    bf16* __restrict__ dtxp)
{
  __shared__ ushort As[64][40];
  __shared__ ushort Ws[64][40];
  const int tile_m = blockIdx.x * 64;
  const int tile_n = blockIdx.y * 64;
  const int t = threadIdx.x;
  const int lane = t & 63;
  const int wave = t >> 6;
  const int wr = (wave >> 1) * 32;
  const int wc = (wave & 1) * 32;
  f32x4 acc[2][2] = {};

  const int kper = ((K + gridDim.z - 1) / gridDim.z + 31) & ~31;
  const int kb = blockIdx.z * kper;
  int ke = kb + kper; if (ke > K) ke = K;

  const int srow = t >> 2;
  const int scol = (t & 3) * 8;

  for (int k0 = kb; k0 < ke; k0 += 32) {
    {
      int gm = tile_m + srow, gk = k0 + scol;
      s16x8 v = {};
      if (gm < M) {
        if (gk + 8 <= K) v = *(const s16x8*)(A + (size_t)gm * lda + gk);
        else {
#pragma unroll
          for (int j = 0; j < 8; j++) if (gk + j < K) v[j] = (short)A[(size_t)gm * lda + gk + j];
        }
      }
      *(s16x8*)&As[srow][scol] = v;
    }
    {
      int gn = tile_n + srow, gk = k0 + scol;
      s16x8 v = {};
      if (gn < N) {
        if (gk + 8 <= K) v = *(const s16x8*)(W + (size_t)gn * ldw + gk);
        else {
#pragma unroll
          for (int j = 0; j < 8; j++) if (gk + j < K) v[j] = (short)W[(size_t)gn * ldw + gk + j];
        }
      }
      *(s16x8*)&Ws[srow][scol] = v;
    }
    __syncthreads();
    const int kk = (lane >> 4) * 8;
    const int fr = lane & 15;
    s16x8 a0 = *(const s16x8*)&As[wr + fr][kk];
    s16x8 a1 = *(const s16x8*)&As[wr + 16 + fr][kk];
    s16x8 b0 = *(const s16x8*)&Ws[wc + fr][kk];
    s16x8 b1 = *(const s16x8*)&Ws[wc + 16 + fr][kk];
    acc[0][0] = __builtin_amdgcn_mfma_f32_16x16x32_bf16(a0, b0, acc[0][0], 0, 0, 0);
    acc[0][1] = __builtin_amdgcn_mfma_f32_16x16x32_bf16(a0, b1, acc[0][1], 0, 0, 0);
    acc[1][0] = __builtin_amdgcn_mfma_f32_16x16x32_bf16(a1, b0, acc[1][0], 0, 0, 0);
    acc[1][1] = __builtin_amdgcn_mfma_f32_16x16x32_bf16(a1, b1, acc[1][1], 0, 0, 0);
    __syncthreads();
  }

  const int fr = lane & 15;
  const int rq = (lane >> 4) * 4;
#pragma unroll
  for (int i = 0; i < 2; i++)
#pragma unroll
    for (int j = 0; j < 2; j++) {
      int colg = tile_n + wc + j * 16 + fr;
#pragma unroll
      for (int r = 0; r < 4; r++) {
        int rowg = tile_m + wr + i * 16 + rq + r;
        if (rowg < M && colg < N) {
          float v = acc[i][j][r];
          size_t idx = (size_t)rowg * ldc + colg;
          if constexpr (MODE == 0) {
            ((bf16*)Cout)[idx] = f2b(v);
          } else if constexpr (MODE == 2) {
            v += bias[colg];
            float sp = (v > 20.f) ? v : log1pf(__expf(v));
            ((float*)Cout)[idx] = sp;
            dtxp[idx] = f2b(sp * b2f(xcb[idx]));
          } else {
            ((float*)Cout)[(size_t)blockIdx.z * (MROWS * XPROJ_N) + idx] = v;
          }
        }
      }
    }
}

// ---------------- causal depthwise conv (D_CONV=4) + bias + silu; 4 c/thread ----------------
__global__ __launch_bounds__(256) void k_conv(const ushort* __restrict__ xz,
    const float* __restrict__ w, const float* __restrict__ cb,
    ushort* __restrict__ xcb) {
  int id4 = blockIdx.x * 256 + threadIdx.x;         // MROWS*DINNER/4 threads
  int m = id4 / (DINNER / 4);
  int c = (id4 - m * (DINNER / 4)) * 4;
  int s = m & (SEQ_LEN - 1);
  f32x4 bias4 = *(const f32x4*)(cb + c);
  float a0 = bias4[0], a1 = bias4[1], a2 = bias4[2], a3 = bias4[3];
  f32x4 w0 = *(const f32x4*)(w + (size_t)c * 4);        // taps for c
  f32x4 w1 = *(const f32x4*)(w + (size_t)(c + 1) * 4);
  f32x4 w2 = *(const f32x4*)(w + (size_t)(c + 2) * 4);
  f32x4 w3 = *(const f32x4*)(w + (size_t)(c + 3) * 4);
#pragma unroll
  for (int k = 0; k < 4; k++) {
    int sp = s - 3 + k;
    if (sp >= 0) {
      ushort4 xv = *(const ushort4*)(xz + (size_t)(m - 3 + k) * (2 * DINNER) + c);
      a0 += w0[k] * us2f(xv.x);
      a1 += w1[k] * us2f(xv.y);
      a2 += w2[k] * us2f(xv.z);
      a3 += w3[k] * us2f(xv.w);
    }
  }
  ushort4 o;
  o.x = (ushort)f2bs(a0 / (1.f + __expf(-a0)));
  o.y = (ushort)f2bs(a1 / (1.f + __expf(-a1)));
  o.z = (ushort)f2bs(a2 / (1.f + __expf(-a2)));
  o.w = (ushort)f2bs(a3 / (1.f + __expf(-a3)));
  *(ushort4*)(xcb + (size_t)m * DINNER + c) = o;
}

// ---------------- chunked selective scan ----------------
__global__ __launch_bounds__(256) void k_scan1(const float* __restrict__ dt,
    const bf16* __restrict__ dtx, const bf16* __restrict__ xdb,
    const float* __restrict__ A_log, float* __restrict__ aprod,
    float* __restrict__ hend) {
  int gid = blockIdx.x * 256 + threadIdx.x;     // SCANW*NCHUNK
  int n  = gid & 15;
  int t2 = gid >> 4;
  int j  = t2 / GROUPS;
  int cb = t2 - j * GROUPS;
  int c  = cb % DINNER;
  int b  = cb / DINNER;
  float Acn = -__expf(A_log[c * DSTATE + n]);
  float h = 0.f, ap = 1.f;
  int mbase = b * SEQ_LEN + j * CHUNK;
#pragma unroll 4
  for (int s = 0; s < CHUNK; s++) {
    int m = mbase + s;
    float dtv = dt[(size_t)m * DINNER + c];
    float dxv = b2f(dtx[(size_t)m * DINNER + c]);
    float Bv  = b2f(xdb[(size_t)m * XPROJ_N + DTRANK + n]);
    float dA  = __expf(dtv * Acn);
    h = h * dA + dxv * Bv;
    ap *= dA;
  }
  aprod[gid] = ap;
  hend[gid]  = h;
}

__global__ __launch_bounds__(256) void k_scan2(const float* __restrict__ aprod,
    const float* __restrict__ hend, float* __restrict__ hin) {
  int idx = blockIdx.x * 256 + threadIdx.x;     // SCANW
  float h = 0.f;
#pragma unroll
  for (int j = 0; j < NCHUNK; j++) {
    hin[(size_t)j * SCANW + idx] = h;
    h = aprod[(size_t)j * SCANW + idx] * h + hend[(size_t)j * SCANW + idx];
  }
}

// scan3 with fused ycomb: p values stashed in LDS (f32), cooperative coalesced
// tail applies (p + D*xc) * silu(z) and writes ybf.
__global__ __launch_bounds__(256) void k_scan3(const float* __restrict__ dt,
    const bf16* __restrict__ dtx, const bf16* __restrict__ xdb,
    const float* __restrict__ A_log, const float* __restrict__ hin,
    const bf16* __restrict__ xcb, const bf16* __restrict__ xz,
    const float* __restrict__ D_ssm, bf16* __restrict__ ybf) {
  __shared__ float p_lds[16][CHUNK + 1];        // +1 pad: conflict-free writes
  int gid = blockIdx.x * 256 + threadIdx.x;     // SCANW*NCHUNK
  int n  = gid & 15;
  int g  = (threadIdx.x >> 4) & 15;             // group within block
  int t2 = gid >> 4;
  int j  = t2 / GROUPS;
  int cb = t2 - j * GROUPS;
  int c  = cb % DINNER;
  int b  = cb / DINNER;
  float Acn = -__expf(A_log[c * DSTATE + n]);
  float h = hin[gid];
  int mbase = b * SEQ_LEN + j * CHUNK;
#pragma unroll 2
  for (int s = 0; s < CHUNK; s++) {
    int m = mbase + s;
    float dtv = dt[(size_t)m * DINNER + c];
    float dxv = b2f(dtx[(size_t)m * DINNER + c]);
    float Bv  = b2f(xdb[(size_t)m * XPROJ_N + DTRANK + n]);
    float Cv  = b2f(xdb[(size_t)m * XPROJ_N + DTRANK + DSTATE + n]);
    float dA  = __expf(dtv * Acn);
    h = h * dA + dxv * Bv;
    float p = h * Cv;
    p += __shfl_xor(p, 8);
    p += __shfl_xor(p, 4);
    p += __shfl_xor(p, 2);
    p += __shfl_xor(p, 1);
    if (n == 0) p_lds[g][s] = p;
  }
  __syncthreads();
  int c0 = c - g;                               // first c of this block
#pragma unroll
  for (int i = 0; i < 4; i++) {
    int idx = threadIdx.x + i * 256;
    int g2 = idx & 15;
    int ml = idx >> 4;
    int m  = mbase + ml;
    int cc = c0 + g2;
    float yv  = p_lds[g2][ml];
    float z   = b2f(xz[(size_t)m * (2 * DINNER) + DINNER + cc]);
    float sil = z / (1.f + __expf(-z));
    float v = (yv + D_ssm[cc] * b2f(xcb[(size_t)m * DINNER + cc])) * sil;
    ybf[(size_t)m * DINNER + cc] = f2b(v);
  }
}

extern "C" void kernel_launch(void* const* d_in, const int* in_sizes, int n_in,
                              void* d_out, int out_size, void* d_ws, size_t ws_size,
                              hipStream_t stream) {
  const int*   tokens    = (const int*)  d_in[0];
  const float* embedding = (const float*)d_in[1];
  const float* head_bias = (const float*)d_in[2];
  const float* ln_g      = (const float*)d_in[3];
  const float* ln_b      = (const float*)d_in[4];
  const float* W_in      = (const float*)d_in[5];
  const float* conv_w    = (const float*)d_in[6];
  const float* conv_b    = (const float*)d_in[7];
  const float* W_xproj   = (const float*)d_in[8];
  const float* W_dt      = (const float*)d_in[9];
  const float* b_dt      = (const float*)d_in[10];
  const float* A_log     = (const float*)d_in[11];
  const float* D_ssm     = (const float*)d_in[12];
  const float* W_out     = (const float*)d_in[13];
  const float* norm_g    = (const float*)d_in[14];
  const float* norm_b    = (const float*)d_in[15];
  float* out = (float*)d_out;

  char* ws = (char*)d_ws;
  size_t off = 0;
  auto alloc = [&](size_t bytes) -> char* {
    char* p = ws + off;
    off = (off + bytes + 255) & ~(size_t)255;
    return p;
  };
  float*  x     = (float*) alloc((size_t)MROWS * DMODEL * 4);
  bf16*   xln   = (bf16*)  alloc((size_t)MROWS * DMODEL * 2);
  bf16*   xz    = (bf16*)  alloc((size_t)MROWS * 2 * DINNER * 2);
  bf16*   xcb   = (bf16*)  alloc((size_t)MROWS * DINNER * 2);
  bf16*   xdb   = (bf16*)  alloc((size_t)MROWS * XPROJ_N * 2);
  float*  xdbp  = (float*) alloc((size_t)XSPLIT * MROWS * XPROJ_N * 4);
  float*  dtf   = (float*) alloc((size_t)MROWS * DINNER * 4);
  bf16*   dtx   = (bf16*)  alloc((size_t)MROWS * DINNER * 2);
  bf16*   ybf   = (bf16*)  alloc((size_t)MROWS * DINNER * 2);
  float*  aprod = (float*) alloc((size_t)SCANW * NCHUNK * 4);
  float*  hend  = (float*) alloc((size_t)SCANW * NCHUNK * 4);
  float*  hin   = (float*) alloc((size_t)SCANW * NCHUNK * 4);
  float*  wpart = (float*) alloc((size_t)WSPLIT * MROWS * DMODEL * 4);
  ushort* ebf   = (ushort*)alloc((size_t)NVOCAB * DMODEL * 2);
  ushort* winb  = (ushort*)alloc((size_t)NLAYERS * 2 * DINNER * DMODEL * 2);
  ushort* wxpb  = (ushort*)alloc((size_t)NLAYERS * XPROJ_N * DINNER * 2);
  ushort* wdtb  = (ushort*)alloc((size_t)NLAYERS * DINNER * DTRANK * 2);
  ushort* woutb = (ushort*)alloc((size_t)NLAYERS * DMODEL * DINNER * 2);
  (void)ws_size; (void)in_sizes; (void)n_in; (void)out_size;

  // all weight conversions f32 -> bf16 in ONE dispatch
  k_cvt5<<<(CVT_E4 + 255) / 256, 256, 0, stream>>>(
      embedding, W_in, W_out, W_xproj, W_dt,
      ebf, winb, woutb, wxpb, wdtb);

  // fused embedding gather + layer-0 LN
  k_embed_ln<<<MROWS, 256, 0, stream>>>(tokens, embedding, x, xln, ln_g, ln_b);

  const int XDBN4 = MROWS * XPROJ_N / 4;          // 40960

  for (int L = 0; L < NLAYERS; L++) {
    // W_in GEMM -> bf16 xz (OMODE=2)
    k_gemm128<false, 2><<<dim3(MROWS / 128, (2 * DINNER) / 128), 512, 0, stream>>>(
        (const ushort*)xln, DMODEL,
        winb + (size_t)L * 2 * DINNER * DMODEL, DMODEL,
        (void*)xz, 2 * DINNER, nullptr, MROWS, 2 * DINNER, DMODEL);

    k_conv<<<MROWS * DINNER / 1024, 256, 0, stream>>>(
        (const ushort*)xz, conv_w + (size_t)L * DINNER * 4,
        conv_b + (size_t)L * DINNER, (ushort*)xcb);

    // xproj GEMM: split-K=8 into per-z f32 partial slices (no atomics), then sum->bf16
    k_gemm<3><<<dim3(MROWS / 64, 2, XSPLIT), 256, 0, stream>>>(
        (const ushort*)xcb, DINNER,
        wxpb + (size_t)L * XPROJ_N * DINNER, DINNER,
        (void*)xdbp, XPROJ_N, MROWS, XPROJ_N, DINNER,
        nullptr, nullptr, nullptr);
    k_xsum<<<(XDBN4 + 255) / 256, 256, 0, stream>>>(xdbp, (ushort*)xdb, XDBN4);

    // dt GEMM with fused softplus(+b_dt) and dtx = bf16(sp*xc)
    k_gemm<2><<<dim3(MROWS / 64, DINNER / 64), 256, 0, stream>>>(
        (const ushort*)xdb, XPROJ_N,
        wdtb + (size_t)L * DINNER * DTRANK, DTRANK,
        (void*)dtf, DINNER, MROWS, DINNER, DTRANK,
        b_dt + (size_t)L * DINNER, xcb, dtx);

    const float* Al = A_log + (size_t)L * DINNER * DSTATE;
    k_scan1<<<SCANW * NCHUNK / 256, 256, 0, stream>>>(dtf, dtx, xdb, Al, aprod, hend);
    k_scan2<<<SCANW / 256, 256, 0, stream>>>(aprod, hend, hin);
    k_scan3<<<SCANW * NCHUNK / 256, 256, 0, stream>>>(
        dtf, dtx, xdb, Al, hin, xcb, xz, D_ssm + (size_t)L * DINNER, ybf);

    // W_out GEMM: split-K=4 into f32 partials (plain stores, no atomics)
    k_gemm128<false, 3><<<dim3(MROWS / 128, DMODEL / 128, WSPLIT), 512, 0, stream>>>(
        (const ushort*)ybf, DINNER,
        woutb + (size_t)L * DMODEL * DINNER, DINNER,
        (void*)wpart, DMODEL, nullptr, MROWS, DMODEL, DINNER);

    // residual-add + LN (next layer's gamma/beta, or final norm after last layer)
    const float* gg = (L < NLAYERS - 1) ? ln_g + (L + 1) * DMODEL : norm_g;
    const float* bb = (L < NLAYERS - 1) ? ln_b + (L + 1) * DMODEL : norm_b;
    k_lnadd<<<MROWS, 256, 0, stream>>>(x, wpart, xln, gg, bb);
  }

  // LM head: 256x256 4-phase deep-pipelined GEMM (2048 x 32000 x 768)
  k_gemmhead<true><<<dim3(MROWS / 256, NVOCAB / 256), 512, 0, stream>>>(
      (const ushort*)xln, DMODEL,
      ebf, DMODEL,
      out, NVOCAB, head_bias, MROWS, NVOCAB, DMODEL);
}

// Round 16
// 888.454 us; speedup vs baseline: 1.0088x; 1.0088x over previous
//
#include <hip/hip_runtime.h>
#include <hip/hip_bf16.h>
#include <cstdint>
#include <cstddef>

#define SEQ_LEN 1024
#define NBATCH  2
#define MROWS   2048          // NBATCH*SEQ_LEN, row index m = b*SEQ_LEN + s
#define DMODEL  768
#define DINNER  1536
#define DTRANK  48
#define DSTATE  16
#define NLAYERS 4
#define NVOCAB  32000
#define XPROJ_N 80            // DTRANK + 2*DSTATE
#define NCHUNK  16
#define CHUNK   64            // SEQ_LEN / NCHUNK
#define GROUPS  (NBATCH * DINNER)          // 3072
#define SCANW   (GROUPS * DSTATE)          // 49152
#define XSPLIT  8             // xproj split-K factor
#define WSPLIT  4             // W_out split-K factor

typedef __attribute__((ext_vector_type(4))) float f32x4;
typedef __attribute__((ext_vector_type(8))) short s16x8;
using bf16 = __hip_bfloat16;

__device__ __forceinline__ float b2f(bf16 v){ return __bfloat162float(v); }
__device__ __forceinline__ bf16  f2b(float v){ return __float2bfloat16(v); }
__device__ __forceinline__ short f2bs(float v){
  return (short)__builtin_bit_cast(unsigned short, __float2bfloat16(v));
}
__device__ __forceinline__ float us2f(ushort u){
  return __bfloat162float(__builtin_bit_cast(bf16, u));
}

// async global->LDS, 16B per lane; LDS dest = (wave-uniform base) + lane*16
__device__ __forceinline__ void glds16(const ushort* g, ushort* l) {
  __builtin_amdgcn_global_load_lds(
      (const __attribute__((address_space(1))) void*)g,
      (__attribute__((address_space(3))) void*)l,
      16, 0, 0);
}

// ---------------- merged f32 -> bf16 convert for all 5 weight tensors ----------------
#define CVT_E0 6144000            // emb     24,576,000 elems /4
#define CVT_E1 (CVT_E0 + 2359296) // + W_in   9,437,184 /4
#define CVT_E2 (CVT_E1 + 1179648) // + W_out  4,718,592 /4
#define CVT_E3 (CVT_E2 + 122880)  // + W_xproj  491,520 /4
#define CVT_E4 (CVT_E3 + 73728)   // + W_dt     294,912 /4
__global__ __launch_bounds__(256) void k_cvt5(
    const float* __restrict__ s0, const float* __restrict__ s1,
    const float* __restrict__ s2, const float* __restrict__ s3,
    const float* __restrict__ s4,
    ushort* __restrict__ d0, ushort* __restrict__ d1,
    ushort* __restrict__ d2, ushort* __restrict__ d3,
    ushort* __restrict__ d4)
{
  int i = blockIdx.x * 256 + threadIdx.x;
  const float* s; ushort* d; int base;
  if      (i < CVT_E0) { s = s0; d = d0; base = 0; }
  else if (i < CVT_E1) { s = s1; d = d1; base = CVT_E0; }
  else if (i < CVT_E2) { s = s2; d = d2; base = CVT_E1; }
  else if (i < CVT_E3) { s = s3; d = d3; base = CVT_E2; }
  else if (i < CVT_E4) { s = s4; d = d4; base = CVT_E3; }
  else return;
  int li = i - base;
  f32x4 v = *(const f32x4*)(s + (size_t)li * 4);
  ushort4 o;
  o.x = (ushort)f2bs(v[0]); o.y = (ushort)f2bs(v[1]);
  o.z = (ushort)f2bs(v[2]); o.w = (ushort)f2bs(v[3]);
  *(ushort4*)(d + (size_t)li * 4) = o;
}

// ---------------- sum XSPLIT f32 partials -> bf16 (xproj split-K reduce) ----------------
__global__ __launch_bounds__(256) void k_xsum(const float* __restrict__ p,
    ushort* __restrict__ out, int n4) {
  int i = blockIdx.x * 256 + threadIdx.x;
  if (i >= n4) return;
  f32x4 s = {};
#pragma unroll
  for (int z = 0; z < XSPLIT; z++) {
    f32x4 v = *(const f32x4*)(p + (size_t)z * (MROWS * XPROJ_N) + (size_t)i * 4);
    s[0] += v[0]; s[1] += v[1]; s[2] += v[2]; s[3] += v[3];
  }
  ushort4 o;
  o.x = (ushort)f2bs(s[0]); o.y = (ushort)f2bs(s[1]);
  o.z = (ushort)f2bs(s[2]); o.w = (ushort)f2bs(s[3]);
  *(ushort4*)(out + (size_t)i * 4) = o;
}

// ---------------- LN body shared by k_embed_ln / k_lnadd ----------------
__device__ __forceinline__ void ln_rows(const float v0[3], int t,
    const float* __restrict__ g, const float* __restrict__ b,
    bf16* __restrict__ outrow) {
  float s = 0.f, s2 = 0.f;
#pragma unroll
  for (int j = 0; j < 3; j++) { s += v0[j]; s2 += v0[j] * v0[j]; }
#pragma unroll
  for (int o = 32; o >= 1; o >>= 1) { s += __shfl_xor(s, o); s2 += __shfl_xor(s2, o); }
  __shared__ float red[8];
  int wave = t >> 6;
  if ((t & 63) == 0) { red[wave] = s; red[4 + wave] = s2; }
  __syncthreads();
  s  = red[0] + red[1] + red[2] + red[3];
  s2 = red[4] + red[5] + red[6] + red[7];
  float mean = s * (1.f / DMODEL);
  float var  = s2 * (1.f / DMODEL) - mean * mean;
  float rstd = rsqrtf(var + 1e-5f);
#pragma unroll
  for (int j = 0; j < 3; j++) {
    int d = t + j * 256;
    outrow[d] = f2b((v0[j] - mean) * rstd * g[d] + b[d]);
  }
}

// ---------------- fused embedding gather + layer-0 LN ----------------
__global__ __launch_bounds__(256) void k_embed_ln(const int* __restrict__ tok,
    const float* __restrict__ emb, float* __restrict__ x,
    bf16* __restrict__ out, const float* __restrict__ g, const float* __restrict__ b) {
  int m = blockIdx.x;
  const float* row = emb + (size_t)tok[m] * DMODEL;
  int t = threadIdx.x;
  float v0[3];
#pragma unroll
  for (int j = 0; j < 3; j++) {
    v0[j] = row[t + j * 256];
    x[(size_t)m * DMODEL + t + j * 256] = v0[j];   // residual base
  }
  ln_rows(v0, t, g, b, out + (size_t)m * DMODEL);
}

// ---------------- residual-add (4 W_out split-K partials) + LayerNorm ----------------
__global__ __launch_bounds__(256) void k_lnadd(float* __restrict__ x,
    const float* __restrict__ part, bf16* __restrict__ out,
    const float* __restrict__ g, const float* __restrict__ b) {
  int m = blockIdx.x;
  int t = threadIdx.x;
  float v0[3];
#pragma unroll
  for (int j = 0; j < 3; j++) {
    int d = t + j * 256;
    size_t idx = (size_t)m * DMODEL + d;
    float v = x[idx];
#pragma unroll
    for (int z = 0; z < WSPLIT; z++) v += part[(size_t)z * (MROWS * DMODEL) + idx];
    x[idx] = v;
    v0[j] = v;
  }
  ln_rows(v0, t, g, b, out + (size_t)m * DMODEL);
}

// ---------------- 128x128 GEMM, 8 waves (W_in / W_out) ----------------
// OMODE: 0 f32, 2 bf16, 3 f32 partial at slice blockIdx.z (stride MROWS*DMODEL).
template<bool HAS_BIAS, int OMODE>
__global__ __launch_bounds__(512, 4) void k_gemm128(
    const ushort* __restrict__ A, int lda,
    const ushort* __restrict__ B, int ldb,
    void* __restrict__ C, int ldc,
    const float* __restrict__ bias,
    int M, int N, int K)
{
  __shared__ ushort As[2][128 * 32];
  __shared__ ushort Bs[2][128 * 32];
  const int t = threadIdx.x;             // 0..511
  const int lane = t & 63;
  const int wave = t >> 6;               // 0..7
  const int tile_m = blockIdx.x * 128;
  const int tile_n = blockIdx.y * 128;
  const int kper = K / gridDim.z;
  const int kb = blockIdx.z * kper;
  const int ke = kb + kper;
  const int wr = (wave >> 1) * 32;       // 4 M-groups of 32
  const int wc = (wave & 1) * 64;        // 2 N-groups of 64

  f32x4 acc[2][4] = {};

  const int sr = wave * 16 + (lane >> 2);
  const int sc = (lane & 3) * 8;
  const ushort* gA = A + (size_t)(tile_m + sr) * lda + sc + kb;
  const ushort* gB = B + (size_t)(tile_n + sr) * ldb + sc + kb;

  const int fr = lane & 15;
  const int kk = (lane >> 4) * 8;

  auto stage = [&](int bb) {
    glds16(gA, &As[bb][wave * 512]);
    glds16(gB, &Bs[bb][wave * 512]);
    gA += 32; gB += 32;
  };

  stage(0);
  int cur = 0;

  for (int k0 = kb; k0 < ke; k0 += 32) {
    if (k0 + 32 < ke) {
      stage(cur ^ 1);                                   // prefetch next tile
      asm volatile("s_waitcnt vmcnt(2)" ::: "memory");  // drain current tile only
    } else {
      asm volatile("s_waitcnt vmcnt(0)" ::: "memory");
    }
    __builtin_amdgcn_s_barrier();

    s16x8 a[2], b[4];
#pragma unroll
    for (int m = 0; m < 2; m++)
      a[m] = *(const s16x8*)&As[cur][(wr + m * 16 + fr) * 32 + kk];
#pragma unroll
    for (int n = 0; n < 4; n++)
      b[n] = *(const s16x8*)&Bs[cur][(wc + n * 16 + fr) * 32 + kk];
#pragma unroll
    for (int m = 0; m < 2; m++)
#pragma unroll
      for (int n = 0; n < 4; n++)
        acc[m][n] = __builtin_amdgcn_mfma_f32_16x16x32_bf16(a[m], b[n], acc[m][n], 0, 0, 0);

    __builtin_amdgcn_s_barrier();
    cur ^= 1;
  }

  const int rq = (lane >> 4) * 4;
#pragma unroll
  for (int m = 0; m < 2; m++)
#pragma unroll
    for (int n = 0; n < 4; n++) {
      int colg = tile_n + wc + n * 16 + fr;
      float bv = HAS_BIAS ? bias[colg] : 0.f;
#pragma unroll
      for (int r = 0; r < 4; r++) {
        int rowg = tile_m + wr + m * 16 + rq + r;
        size_t idx = (size_t)rowg * ldc + colg;
        float v = acc[m][n][r] + bv;
        if constexpr (OMODE == 0) ((float*)C)[idx] = v;
        else if constexpr (OMODE == 2) ((bf16*)C)[idx] = f2b(v);
        else ((float*)C)[(size_t)blockIdx.z * (MROWS * DMODEL) + idx] = v;
      }
    }
}

// ---------------- 256x128 head GEMM (proven best): 8 waves, each 64x64 ----------------
// 16 MFMA per wave per K-step between barriers. BK=32, depth-1 prefetch,
// counted vmcnt(3). LDS 48KB, 40% occupancy. 161-171us = the 2-phase
// structural ceiling (m233); the full 4-phase deep pipeline (r15: 0 bank
// conflicts, race-free, counted vmcnt) landed at the same 165us -> at
// 1 block/CU intra-block pipelining only offsets the lost TLP. Keep 2-phase.
template<bool HAS_BIAS>
__global__ __launch_bounds__(512, 4) void k_gemmhead(
    const ushort* __restrict__ A, int lda,
    const ushort* __restrict__ B, int ldb,
    float* __restrict__ C, int ldc,
    const float* __restrict__ bias,
    int M, int N, int K)
{
  __shared__ ushort As[2][256 * 32];     // 16 KB per buffer
  __shared__ ushort Bs[2][128 * 32];     //  8 KB per buffer
  const int t = threadIdx.x;             // 0..511
  const int lane = t & 63;
  const int wave = t >> 6;               // 0..7
  const int tile_m = blockIdx.x * 256;
  const int tile_n = blockIdx.y * 128;
  const int wr = (wave >> 1) * 64;       // 4 M-groups of 64
  const int wc = (wave & 1) * 64;        // 2 N-groups of 64

  f32x4 acc[4][4] = {};

  const int sr = wave * 16 + (lane >> 2);
  const int sc = (lane & 3) * 8;
  const ushort* gA0 = A + (size_t)(tile_m + sr) * lda + sc;
  const ushort* gA1 = A + (size_t)(tile_m + 128 + sr) * lda + sc;
  const ushort* gB  = B + (size_t)(tile_n + sr) * ldb + sc;

  const int fr = lane & 15;
  const int kk = (lane >> 4) * 8;

  auto stage = [&](int bb) {
    glds16(gA0, &As[bb][wave * 512]);
    glds16(gA1, &As[bb][4096 + wave * 512]);
    glds16(gB,  &Bs[bb][wave * 512]);
    gA0 += 32; gA1 += 32; gB += 32;
  };

  stage(0);
  int cur = 0;

  for (int k0 = 0; k0 < K; k0 += 32) {
    if (k0 + 32 < K) {
      stage(cur ^ 1);                                   // prefetch next tile
      asm volatile("s_waitcnt vmcnt(3)" ::: "memory");  // drain current tile only
    } else {
      asm volatile("s_waitcnt vmcnt(0)" ::: "memory");
    }
    __builtin_amdgcn_s_barrier();

    s16x8 a[4], b[4];
#pragma unroll
    for (int m = 0; m < 4; m++)
      a[m] = *(const s16x8*)&As[cur][(wr + m * 16 + fr) * 32 + kk];
#pragma unroll
    for (int n = 0; n < 4; n++)
      b[n] = *(const s16x8*)&Bs[cur][(wc + n * 16 + fr) * 32 + kk];
#pragma unroll
    for (int m = 0; m < 4; m++)
#pragma unroll
      for (int n = 0; n < 4; n++)
        acc[m][n] = __builtin_amdgcn_mfma_f32_16x16x32_bf16(a[m], b[n], acc[m][n], 0, 0, 0);

    __builtin_amdgcn_s_barrier();
    cur ^= 1;
  }

  const int rq = (lane >> 4) * 4;
#pragma unroll
  for (int m = 0; m < 4; m++)
#pragma unroll
    for (int n = 0; n < 4; n++) {
      int colg = tile_n + wc + n * 16 + fr;
      float bv = HAS_BIAS ? bias[colg] : 0.f;
#pragma unroll
      for (int r = 0; r < 4; r++) {
        int rowg = tile_m + wr + m * 16 + rq + r;
        C[(size_t)rowg * ldc + colg] = acc[m][n][r] + bv;
      }
    }
}

// ---------------- small GEMM (bounds-checked 64x64): C = A * W^T, bf16 inputs ----------------
// MODE: 0 = bf16 out
//       2 = dt-fused: sp=softplus(acc+bias[col]) -> dtf[idx]=bf16(sp),
//           dtx[idx]=bf16(sp*xcb[idx])
//       3 = f32 partial out at slice blockIdx.z (xproj split-K; stride MROWS*XPROJ_N)
template<int MODE>
__global__ __launch_bounds__(256) void k_gemm(
    const ushort* __restrict__ A, int lda,
    const ushort* __restrict__ W, int ldw,
    void* __restrict__ Cout, int ldc,
    int M, int N, int K,
    const float* __restrict__ bias,
    const bf16* __restrict__ xcb,
    bf16* __restrict__ dtxp)
{
  __shared__ ushort As[64][40];
  __shared__ ushort Ws[64][40];
  const int tile_m = blockIdx.x * 64;
  const int tile_n = blockIdx.y * 64;
  const int t = threadIdx.x;
  const int lane = t & 63;
  const int wave = t >> 6;
  const int wr = (wave >> 1) * 32;
  const int wc = (wave & 1) * 32;
  f32x4 acc[2][2] = {};

  const int kper = ((K + gridDim.z - 1) / gridDim.z + 31) & ~31;
  const int kb = blockIdx.z * kper;
  int ke = kb + kper; if (ke > K) ke = K;

  const int srow = t >> 2;
  const int scol = (t & 3) * 8;

  for (int k0 = kb; k0 < ke; k0 += 32) {
    {
      int gm = tile_m + srow, gk = k0 + scol;
      s16x8 v = {};
      if (gm < M) {
        if (gk + 8 <= K) v = *(const s16x8*)(A + (size_t)gm * lda + gk);
        else {
#pragma unroll
          for (int j = 0; j < 8; j++) if (gk + j < K) v[j] = (short)A[(size_t)gm * lda + gk + j];
        }
      }
      *(s16x8*)&As[srow][scol] = v;
    }
    {
      int gn = tile_n + srow, gk = k0 + scol;
      s16x8 v = {};
      if (gn < N) {
        if (gk + 8 <= K) v = *(const s16x8*)(W + (size_t)gn * ldw + gk);
        else {
#pragma unroll
          for (int j = 0; j < 8; j++) if (gk + j < K) v[j] = (short)W[(size_t)gn * ldw + gk + j];
        }
      }
      *(s16x8*)&Ws[srow][scol] = v;
    }
    __syncthreads();
    const int kk = (lane >> 4) * 8;
    const int fr = lane & 15;
    s16x8 a0 = *(const s16x8*)&As[wr + fr][kk];
    s16x8 a1 = *(const s16x8*)&As[wr + 16 + fr][kk];
    s16x8 b0 = *(const s16x8*)&Ws[wc + fr][kk];
    s16x8 b1 = *(const s16x8*)&Ws[wc + 16 + fr][kk];
    acc[0][0] = __builtin_amdgcn_mfma_f32_16x16x32_bf16(a0, b0, acc[0][0], 0, 0, 0);
    acc[0][1] = __builtin_amdgcn_mfma_f32_16x16x32_bf16(a0, b1, acc[0][1], 0, 0, 0);
    acc[1][0] = __builtin_amdgcn_mfma_f32_16x16x32_bf16(a1, b0, acc[1][0], 0, 0, 0);
    acc[1][1] = __builtin_amdgcn_mfma_f32_16x16x32_bf16(a1, b1, acc[1][1], 0, 0, 0);
    __syncthreads();
  }

  const int fr = lane & 15;
  const int rq = (lane >> 4) * 4;
#pragma unroll
  for (int i = 0; i < 2; i++)
#pragma unroll
    for (int j = 0; j < 2; j++) {
      int colg = tile_n + wc + j * 16 + fr;
#pragma unroll
      for (int r = 0; r < 4; r++) {
        int rowg = tile_m + wr + i * 16 + rq + r;
        if (rowg < M && colg < N) {
          float v = acc[i][j][r];
          size_t idx = (size_t)rowg * ldc + colg;
          if constexpr (MODE == 0) {
            ((bf16*)Cout)[idx] = f2b(v);
          } else if constexpr (MODE == 2) {
            v += bias[colg];
            float sp = (v > 20.f) ? v : log1pf(__expf(v));
            ((bf16*)Cout)[idx] = f2b(sp);
            dtxp[idx] = f2b(sp * b2f(xcb[idx]));
          } else {
            ((float*)Cout)[(size_t)blockIdx.z * (MROWS * XPROJ_N) + idx] = v;
          }
        }
      }
    }
}

// ---------------- causal depthwise conv (D_CONV=4) + bias + silu; 4 c/thread ----------------
__global__ __launch_bounds__(256) void k_conv(const ushort* __restrict__ xz,
    const float* __restrict__ w, const float* __restrict__ cb,
    ushort* __restrict__ xcb) {
  int id4 = blockIdx.x * 256 + threadIdx.x;         // MROWS*DINNER/4 threads
  int m = id4 / (DINNER / 4);
  int c = (id4 - m * (DINNER / 4)) * 4;
  int s = m & (SEQ_LEN - 1);
  f32x4 bias4 = *(const f32x4*)(cb + c);
  float a0 = bias4[0], a1 = bias4[1], a2 = bias4[2], a3 = bias4[3];
  f32x4 w0 = *(const f32x4*)(w + (size_t)c * 4);        // taps for c
  f32x4 w1 = *(const f32x4*)(w + (size_t)(c + 1) * 4);
  f32x4 w2 = *(const f32x4*)(w + (size_t)(c + 2) * 4);
  f32x4 w3 = *(const f32x4*)(w + (size_t)(c + 3) * 4);
#pragma unroll
  for (int k = 0; k < 4; k++) {
    int sp = s - 3 + k;
    if (sp >= 0) {
      ushort4 xv = *(const ushort4*)(xz + (size_t)(m - 3 + k) * (2 * DINNER) + c);
      a0 += w0[k] * us2f(xv.x);
      a1 += w1[k] * us2f(xv.y);
      a2 += w2[k] * us2f(xv.z);
      a3 += w3[k] * us2f(xv.w);
    }
  }
  ushort4 o;
  o.x = (ushort)f2bs(a0 / (1.f + __expf(-a0)));
  o.y = (ushort)f2bs(a1 / (1.f + __expf(-a1)));
  o.z = (ushort)f2bs(a2 / (1.f + __expf(-a2)));
  o.w = (ushort)f2bs(a3 / (1.f + __expf(-a3)));
  *(ushort4*)(xcb + (size_t)m * DINNER + c) = o;
}

// ---------------- chunked selective scan ----------------
__global__ __launch_bounds__(256) void k_scan1(const bf16* __restrict__ dt,
    const bf16* __restrict__ dtx, const bf16* __restrict__ xdb,
    const float* __restrict__ A_log, float* __restrict__ aprod,
    float* __restrict__ hend) {
  int gid = blockIdx.x * 256 + threadIdx.x;     // SCANW*NCHUNK
  int n  = gid & 15;
  int t2 = gid >> 4;
  int j  = t2 / GROUPS;
  int cb = t2 - j * GROUPS;
  int c  = cb % DINNER;
  int b  = cb / DINNER;
  float Acn = -__expf(A_log[c * DSTATE + n]);
  float h = 0.f, ap = 1.f;
  int mbase = b * SEQ_LEN + j * CHUNK;
#pragma unroll 4
  for (int s = 0; s < CHUNK; s++) {
    int m = mbase + s;
    float dtv = b2f(dt[(size_t)m * DINNER + c]);
    float dxv = b2f(dtx[(size_t)m * DINNER + c]);
    float Bv  = b2f(xdb[(size_t)m * XPROJ_N + DTRANK + n]);
    float dA  = __expf(dtv * Acn);
    h = h * dA + dxv * Bv;
    ap *= dA;
  }
  aprod[gid] = ap;
  hend[gid]  = h;
}

__global__ __launch_bounds__(256) void k_scan2(const float* __restrict__ aprod,
    const float* __restrict__ hend, float* __restrict__ hin) {
  int idx = blockIdx.x * 256 + threadIdx.x;     // SCANW
  float h = 0.f;
#pragma unroll
  for (int j = 0; j < NCHUNK; j++) {
    hin[(size_t)j * SCANW + idx] = h;
    h = aprod[(size_t)j * SCANW + idx] * h + hend[(size_t)j * SCANW + idx];
  }
}

// scan3 with fused ycomb: p values stashed in LDS (f32), cooperative coalesced
// tail applies (p + D*xc) * silu(z) and writes ybf.
__global__ __launch_bounds__(256) void k_scan3(const bf16* __restrict__ dt,
    const bf16* __restrict__ dtx, const bf16* __restrict__ xdb,
    const float* __restrict__ A_log, const float* __restrict__ hin,
    const bf16* __restrict__ xcb, const bf16* __restrict__ xz,
    const float* __restrict__ D_ssm, bf16* __restrict__ ybf) {
  __shared__ float p_lds[16][CHUNK + 1];        // +1 pad: conflict-free writes
  int gid = blockIdx.x * 256 + threadIdx.x;     // SCANW*NCHUNK
  int n  = gid & 15;
  int g  = (threadIdx.x >> 4) & 15;             // group within block
  int t2 = gid >> 4;
  int j  = t2 / GROUPS;
  int cb = t2 - j * GROUPS;
  int c  = cb % DINNER;
  int b  = cb / DINNER;
  float Acn = -__expf(A_log[c * DSTATE + n]);
  float h = hin[gid];
  int mbase = b * SEQ_LEN + j * CHUNK;
#pragma unroll 2
  for (int s = 0; s < CHUNK; s++) {
    int m = mbase + s;
    float dtv = b2f(dt[(size_t)m * DINNER + c]);
    float dxv = b2f(dtx[(size_t)m * DINNER + c]);
    float Bv  = b2f(xdb[(size_t)m * XPROJ_N + DTRANK + n]);
    float Cv  = b2f(xdb[(size_t)m * XPROJ_N + DTRANK + DSTATE + n]);
    float dA  = __expf(dtv * Acn);
    h = h * dA + dxv * Bv;
    float p = h * Cv;
    p += __shfl_xor(p, 8);
    p += __shfl_xor(p, 4);
    p += __shfl_xor(p, 2);
    p += __shfl_xor(p, 1);
    if (n == 0) p_lds[g][s] = p;
  }
  __syncthreads();
  int c0 = c - g;                               // first c of this block
#pragma unroll
  for (int i = 0; i < 4; i++) {
    int idx = threadIdx.x + i * 256;
    int g2 = idx & 15;
    int ml = idx >> 4;
    int m  = mbase + ml;
    int cc = c0 + g2;
    float yv  = p_lds[g2][ml];
    float z   = b2f(xz[(size_t)m * (2 * DINNER) + DINNER + cc]);
    float sil = z / (1.f + __expf(-z));
    float v = (yv + D_ssm[cc] * b2f(xcb[(size_t)m * DINNER + cc])) * sil;
    ybf[(size_t)m * DINNER + cc] = f2b(v);
  }
}

extern "C" void kernel_launch(void* const* d_in, const int* in_sizes, int n_in,
                              void* d_out, int out_size, void* d_ws, size_t ws_size,
                              hipStream_t stream) {
  const int*   tokens    = (const int*)  d_in[0];
  const float* embedding = (const float*)d_in[1];
  const float* head_bias = (const float*)d_in[2];
  const float* ln_g      = (const float*)d_in[3];
  const float* ln_b      = (const float*)d_in[4];
  const float* W_in      = (const float*)d_in[5];
  const float* conv_w    = (const float*)d_in[6];
  const float* conv_b    = (const float*)d_in[7];
  const float* W_xproj   = (const float*)d_in[8];
  const float* W_dt      = (const float*)d_in[9];
  const float* b_dt      = (const float*)d_in[10];
  const float* A_log     = (const float*)d_in[11];
  const float* D_ssm     = (const float*)d_in[12];
  const float* W_out     = (const float*)d_in[13];
  const float* norm_g    = (const float*)d_in[14];
  const float* norm_b    = (const float*)d_in[15];
  float* out = (float*)d_out;

  char* ws = (char*)d_ws;
  size_t off = 0;
  auto alloc = [&](size_t bytes) -> char* {
    char* p = ws + off;
    off = (off + bytes + 255) & ~(size_t)255;
    return p;
  };
  float*  x     = (float*) alloc((size_t)MROWS * DMODEL * 4);
  bf16*   xln   = (bf16*)  alloc((size_t)MROWS * DMODEL * 2);
  bf16*   xz    = (bf16*)  alloc((size_t)MROWS * 2 * DINNER * 2);
  bf16*   xcb   = (bf16*)  alloc((size_t)MROWS * DINNER * 2);
  bf16*   xdb   = (bf16*)  alloc((size_t)MROWS * XPROJ_N * 2);
  float*  xdbp  = (float*) alloc((size_t)XSPLIT * MROWS * XPROJ_N * 4);
  bf16*   dtf   = (bf16*)  alloc((size_t)MROWS * DINNER * 2);
  bf16*   dtx   = (bf16*)  alloc((size_t)MROWS * DINNER * 2);
  bf16*   ybf   = (bf16*)  alloc((size_t)MROWS * DINNER * 2);
  float*  aprod = (float*) alloc((size_t)SCANW * NCHUNK * 4);
  float*  hend  = (float*) alloc((size_t)SCANW * NCHUNK * 4);
  float*  hin   = (float*) alloc((size_t)SCANW * NCHUNK * 4);
  float*  wpart = (float*) alloc((size_t)WSPLIT * MROWS * DMODEL * 4);
  ushort* ebf   = (ushort*)alloc((size_t)NVOCAB * DMODEL * 2);
  ushort* winb  = (ushort*)alloc((size_t)NLAYERS * 2 * DINNER * DMODEL * 2);
  ushort* wxpb  = (ushort*)alloc((size_t)NLAYERS * XPROJ_N * DINNER * 2);
  ushort* wdtb  = (ushort*)alloc((size_t)NLAYERS * DINNER * DTRANK * 2);
  ushort* woutb = (ushort*)alloc((size_t)NLAYERS * DMODEL * DINNER * 2);
  (void)ws_size; (void)in_sizes; (void)n_in; (void)out_size;

  // all weight conversions f32 -> bf16 in ONE dispatch
  k_cvt5<<<(CVT_E4 + 255) / 256, 256, 0, stream>>>(
      embedding, W_in, W_out, W_xproj, W_dt,
      ebf, winb, woutb, wxpb, wdtb);

  // fused embedding gather + layer-0 LN
  k_embed_ln<<<MROWS, 256, 0, stream>>>(tokens, embedding, x, xln, ln_g, ln_b);

  const int XDBN4 = MROWS * XPROJ_N / 4;          // 40960

  for (int L = 0; L < NLAYERS; L++) {
    // W_in GEMM -> bf16 xz (OMODE=2)
    k_gemm128<false, 2><<<dim3(MROWS / 128, (2 * DINNER) / 128), 512, 0, stream>>>(
        (const ushort*)xln, DMODEL,
        winb + (size_t)L * 2 * DINNER * DMODEL, DMODEL,
        (void*)xz, 2 * DINNER, nullptr, MROWS, 2 * DINNER, DMODEL);

    k_conv<<<MROWS * DINNER / 1024, 256, 0, stream>>>(
        (const ushort*)xz, conv_w + (size_t)L * DINNER * 4,
        conv_b + (size_t)L * DINNER, (ushort*)xcb);

    // xproj GEMM: split-K=8 into per-z f32 partial slices (no atomics), then sum->bf16
    k_gemm<3><<<dim3(MROWS / 64, 2, XSPLIT), 256, 0, stream>>>(
        (const ushort*)xcb, DINNER,
        wxpb + (size_t)L * XPROJ_N * DINNER, DINNER,
        (void*)xdbp, XPROJ_N, MROWS, XPROJ_N, DINNER,
        nullptr, nullptr, nullptr);
    k_xsum<<<(XDBN4 + 255) / 256, 256, 0, stream>>>(xdbp, (ushort*)xdb, XDBN4);

    // dt GEMM with fused softplus(+b_dt): dtf = bf16(sp), dtx = bf16(sp*xc)
    k_gemm<2><<<dim3(MROWS / 64, DINNER / 64), 256, 0, stream>>>(
        (const ushort*)xdb, XPROJ_N,
        wdtb + (size_t)L * DINNER * DTRANK, DTRANK,
        (void*)dtf, DINNER, MROWS, DINNER, DTRANK,
        b_dt + (size_t)L * DINNER, xcb, dtx);

    const float* Al = A_log + (size_t)L * DINNER * DSTATE;
    k_scan1<<<SCANW * NCHUNK / 256, 256, 0, stream>>>(dtf, dtx, xdb, Al, aprod, hend);
    k_scan2<<<SCANW / 256, 256, 0, stream>>>(aprod, hend, hin);
    k_scan3<<<SCANW * NCHUNK / 256, 256, 0, stream>>>(
        dtf, dtx, xdb, Al, hin, xcb, xz, D_ssm + (size_t)L * DINNER, ybf);

    // W_out GEMM: split-K=4 into f32 partials (plain stores, no atomics)
    k_gemm128<false, 3><<<dim3(MROWS / 128, DMODEL / 128, WSPLIT), 512, 0, stream>>>(
        (const ushort*)ybf, DINNER,
        woutb + (size_t)L * DMODEL * DINNER, DINNER,
        (void*)wpart, DMODEL, nullptr, MROWS, DMODEL, DINNER);

    // residual-add + LN (next layer's gamma/beta, or final norm after last layer)
    const float* gg = (L < NLAYERS - 1) ? ln_g + (L + 1) * DMODEL : norm_g;
    const float* bb = (L < NLAYERS - 1) ? ln_b + (L + 1) * DMODEL : norm_b;
    k_lnadd<<<MROWS, 256, 0, stream>>>(x, wpart, xln, gg, bb);
  }

  // LM head: 256x128-tile BK=32 GEMM (2048 x 32000 x 768), f32 out + bias
  k_gemmhead<true><<<dim3(MROWS / 256, NVOCAB / 128), 512, 0, stream>>>(
      (const ushort*)xln, DMODEL,
      ebf, DMODEL,
      out, NVOCAB, head_bias, MROWS, NVOCAB, DMODEL);
}

// Round 17
// 886.046 us; speedup vs baseline: 1.0115x; 1.0027x over previous
//
#include <hip/hip_runtime.h>
#include <hip/hip_bf16.h>
#include <cstdint>
#include <cstddef>

#define SEQ_LEN 1024
#define NBATCH  2
#define MROWS   2048          // NBATCH*SEQ_LEN, row index m = b*SEQ_LEN + s
#define DMODEL  768
#define DINNER  1536
#define DTRANK  48
#define DSTATE  16
#define NLAYERS 4
#define NVOCAB  32000
#define XPROJ_N 80            // DTRANK + 2*DSTATE
#define NCHUNK  16
#define CHUNK   64            // SEQ_LEN / NCHUNK
#define GROUPS  (NBATCH * DINNER)          // 3072
#define SCANW   (GROUPS * DSTATE)          // 49152
#define XSPLIT  8             // xproj split-K factor
#define WSPLIT  4             // W_out split-K factor

typedef __attribute__((ext_vector_type(4))) float f32x4;
typedef __attribute__((ext_vector_type(8))) short s16x8;
using bf16 = __hip_bfloat16;

__device__ __forceinline__ float b2f(bf16 v){ return __bfloat162float(v); }
__device__ __forceinline__ bf16  f2b(float v){ return __float2bfloat16(v); }
__device__ __forceinline__ short f2bs(float v){
  return (short)__builtin_bit_cast(unsigned short, __float2bfloat16(v));
}
__device__ __forceinline__ float us2f(ushort u){
  return __bfloat162float(__builtin_bit_cast(bf16, u));
}

// async global->LDS, 16B per lane; LDS dest = (wave-uniform base) + lane*16
__device__ __forceinline__ void glds16(const ushort* g, ushort* l) {
  __builtin_amdgcn_global_load_lds(
      (const __attribute__((address_space(1))) void*)g,
      (__attribute__((address_space(3))) void*)l,
      16, 0, 0);
}

// ---------------- merged f32 -> bf16 convert for all 5 weight tensors ----------------
#define CVT_E0 6144000            // emb     24,576,000 elems /4
#define CVT_E1 (CVT_E0 + 2359296) // + W_in   9,437,184 /4
#define CVT_E2 (CVT_E1 + 1179648) // + W_out  4,718,592 /4
#define CVT_E3 (CVT_E2 + 122880)  // + W_xproj  491,520 /4
#define CVT_E4 (CVT_E3 + 73728)   // + W_dt     294,912 /4
__global__ __launch_bounds__(256) void k_cvt5(
    const float* __restrict__ s0, const float* __restrict__ s1,
    const float* __restrict__ s2, const float* __restrict__ s3,
    const float* __restrict__ s4,
    ushort* __restrict__ d0, ushort* __restrict__ d1,
    ushort* __restrict__ d2, ushort* __restrict__ d3,
    ushort* __restrict__ d4)
{
  int i = blockIdx.x * 256 + threadIdx.x;
  const float* s; ushort* d; int base;
  if      (i < CVT_E0) { s = s0; d = d0; base = 0; }
  else if (i < CVT_E1) { s = s1; d = d1; base = CVT_E0; }
  else if (i < CVT_E2) { s = s2; d = d2; base = CVT_E1; }
  else if (i < CVT_E3) { s = s3; d = d3; base = CVT_E2; }
  else if (i < CVT_E4) { s = s4; d = d4; base = CVT_E3; }
  else return;
  int li = i - base;
  f32x4 v = *(const f32x4*)(s + (size_t)li * 4);
  ushort4 o;
  o.x = (ushort)f2bs(v[0]); o.y = (ushort)f2bs(v[1]);
  o.z = (ushort)f2bs(v[2]); o.w = (ushort)f2bs(v[3]);
  *(ushort4*)(d + (size_t)li * 4) = o;
}

// ---------------- sum XSPLIT f32 partials -> bf16 (xproj split-K reduce) ----------------
__global__ __launch_bounds__(256) void k_xsum(const float* __restrict__ p,
    ushort* __restrict__ out, int n4) {
  int i = blockIdx.x * 256 + threadIdx.x;
  if (i >= n4) return;
  f32x4 s = {};
#pragma unroll
  for (int z = 0; z < XSPLIT; z++) {
    f32x4 v = *(const f32x4*)(p + (size_t)z * (MROWS * XPROJ_N) + (size_t)i * 4);
    s[0] += v[0]; s[1] += v[1]; s[2] += v[2]; s[3] += v[3];
  }
  ushort4 o;
  o.x = (ushort)f2bs(s[0]); o.y = (ushort)f2bs(s[1]);
  o.z = (ushort)f2bs(s[2]); o.w = (ushort)f2bs(s[3]);
  *(ushort4*)(out + (size_t)i * 4) = o;
}

// ---------------- LN body shared by k_embed_ln / k_lnadd ----------------
__device__ __forceinline__ void ln_rows(const float v0[3], int t,
    const float* __restrict__ g, const float* __restrict__ b,
    bf16* __restrict__ outrow) {
  float s = 0.f, s2 = 0.f;
#pragma unroll
  for (int j = 0; j < 3; j++) { s += v0[j]; s2 += v0[j] * v0[j]; }
#pragma unroll
  for (int o = 32; o >= 1; o >>= 1) { s += __shfl_xor(s, o); s2 += __shfl_xor(s2, o); }
  __shared__ float red[8];
  int wave = t >> 6;
  if ((t & 63) == 0) { red[wave] = s; red[4 + wave] = s2; }
  __syncthreads();
  s  = red[0] + red[1] + red[2] + red[3];
  s2 = red[4] + red[5] + red[6] + red[7];
  float mean = s * (1.f / DMODEL);
  float var  = s2 * (1.f / DMODEL) - mean * mean;
  float rstd = rsqrtf(var + 1e-5f);
#pragma unroll
  for (int j = 0; j < 3; j++) {
    int d = t + j * 256;
    outrow[d] = f2b((v0[j] - mean) * rstd * g[d] + b[d]);
  }
}

// ---------------- fused embedding gather + layer-0 LN ----------------
__global__ __launch_bounds__(256) void k_embed_ln(const int* __restrict__ tok,
    const float* __restrict__ emb, float* __restrict__ x,
    bf16* __restrict__ out, const float* __restrict__ g, const float* __restrict__ b) {
  int m = blockIdx.x;
  const float* row = emb + (size_t)tok[m] * DMODEL;
  int t = threadIdx.x;
  float v0[3];
#pragma unroll
  for (int j = 0; j < 3; j++) {
    v0[j] = row[t + j * 256];
    x[(size_t)m * DMODEL + t + j * 256] = v0[j];   // residual base
  }
  ln_rows(v0, t, g, b, out + (size_t)m * DMODEL);
}

// ---------------- residual-add (4 W_out split-K partials) + LayerNorm ----------------
__global__ __launch_bounds__(256) void k_lnadd(float* __restrict__ x,
    const float* __restrict__ part, bf16* __restrict__ out,
    const float* __restrict__ g, const float* __restrict__ b) {
  int m = blockIdx.x;
  int t = threadIdx.x;
  float v0[3];
#pragma unroll
  for (int j = 0; j < 3; j++) {
    int d = t + j * 256;
    size_t idx = (size_t)m * DMODEL + d;
    float v = x[idx];
#pragma unroll
    for (int z = 0; z < WSPLIT; z++) v += part[(size_t)z * (MROWS * DMODEL) + idx];
    x[idx] = v;
    v0[j] = v;
  }
  ln_rows(v0, t, g, b, out + (size_t)m * DMODEL);
}

// ---------------- 128x128 GEMM, 8 waves (W_in / W_out) ----------------
// OMODE: 0 f32, 2 bf16, 3 f32 partial at slice blockIdx.z (stride MROWS*DMODEL).
template<bool HAS_BIAS, int OMODE>
__global__ __launch_bounds__(512, 4) void k_gemm128(
    const ushort* __restrict__ A, int lda,
    const ushort* __restrict__ B, int ldb,
    void* __restrict__ C, int ldc,
    const float* __restrict__ bias,
    int M, int N, int K)
{
  __shared__ ushort As[2][128 * 32];
  __shared__ ushort Bs[2][128 * 32];
  const int t = threadIdx.x;             // 0..511
  const int lane = t & 63;
  const int wave = t >> 6;               // 0..7
  const int tile_m = blockIdx.x * 128;
  const int tile_n = blockIdx.y * 128;
  const int kper = K / gridDim.z;
  const int kb = blockIdx.z * kper;
  const int ke = kb + kper;
  const int wr = (wave >> 1) * 32;       // 4 M-groups of 32
  const int wc = (wave & 1) * 64;        // 2 N-groups of 64

  f32x4 acc[2][4] = {};

  const int sr = wave * 16 + (lane >> 2);
  const int sc = (lane & 3) * 8;
  const ushort* gA = A + (size_t)(tile_m + sr) * lda + sc + kb;
  const ushort* gB = B + (size_t)(tile_n + sr) * ldb + sc + kb;

  const int fr = lane & 15;
  const int kk = (lane >> 4) * 8;

  auto stage = [&](int bb) {
    glds16(gA, &As[bb][wave * 512]);
    glds16(gB, &Bs[bb][wave * 512]);
    gA += 32; gB += 32;
  };

  stage(0);
  int cur = 0;

  for (int k0 = kb; k0 < ke; k0 += 32) {
    if (k0 + 32 < ke) {
      stage(cur ^ 1);                                   // prefetch next tile
      asm volatile("s_waitcnt vmcnt(2)" ::: "memory");  // drain current tile only
    } else {
      asm volatile("s_waitcnt vmcnt(0)" ::: "memory");
    }
    __builtin_amdgcn_s_barrier();

    s16x8 a[2], b[4];
#pragma unroll
    for (int m = 0; m < 2; m++)
      a[m] = *(const s16x8*)&As[cur][(wr + m * 16 + fr) * 32 + kk];
#pragma unroll
    for (int n = 0; n < 4; n++)
      b[n] = *(const s16x8*)&Bs[cur][(wc + n * 16 + fr) * 32 + kk];
#pragma unroll
    for (int m = 0; m < 2; m++)
#pragma unroll
      for (int n = 0; n < 4; n++)
        acc[m][n] = __builtin_amdgcn_mfma_f32_16x16x32_bf16(a[m], b[n], acc[m][n], 0, 0, 0);

    __builtin_amdgcn_s_barrier();
    cur ^= 1;
  }

  const int rq = (lane >> 4) * 4;
#pragma unroll
  for (int m = 0; m < 2; m++)
#pragma unroll
    for (int n = 0; n < 4; n++) {
      int colg = tile_n + wc + n * 16 + fr;
      float bv = HAS_BIAS ? bias[colg] : 0.f;
#pragma unroll
      for (int r = 0; r < 4; r++) {
        int rowg = tile_m + wr + m * 16 + rq + r;
        size_t idx = (size_t)rowg * ldc + colg;
        float v = acc[m][n][r] + bv;
        if constexpr (OMODE == 0) ((float*)C)[idx] = v;
        else if constexpr (OMODE == 2) ((bf16*)C)[idx] = f2b(v);
        else ((float*)C)[(size_t)blockIdx.z * (MROWS * DMODEL) + idx] = v;
      }
    }
}

// ---------------- 256x128 head GEMM (proven best): 8 waves, each 64x64 ----------------
// 16 MFMA per wave per K-step between barriers. BK=32, depth-1 prefetch,
// counted vmcnt(3). LDS 48KB, 40% occupancy. 161-171us = the 2-phase
// structural ceiling (m233); the full 4-phase deep pipeline (r15: 0 bank
// conflicts, race-free, counted vmcnt) landed at the same 165us -> at
// 1 block/CU intra-block pipelining only offsets the lost TLP. Keep 2-phase.
template<bool HAS_BIAS>
__global__ __launch_bounds__(512, 4) void k_gemmhead(
    const ushort* __restrict__ A, int lda,
    const ushort* __restrict__ B, int ldb,
    float* __restrict__ C, int ldc,
    const float* __restrict__ bias,
    int M, int N, int K)
{
  __shared__ ushort As[2][256 * 32];     // 16 KB per buffer
  __shared__ ushort Bs[2][128 * 32];     //  8 KB per buffer
  const int t = threadIdx.x;             // 0..511
  const int lane = t & 63;
  const int wave = t >> 6;               // 0..7
  const int tile_m = blockIdx.x * 256;
  const int tile_n = blockIdx.y * 128;
  const int wr = (wave >> 1) * 64;       // 4 M-groups of 64
  const int wc = (wave & 1) * 64;        // 2 N-groups of 64

  f32x4 acc[4][4] = {};

  const int sr = wave * 16 + (lane >> 2);
  const int sc = (lane & 3) * 8;
  const ushort* gA0 = A + (size_t)(tile_m + sr) * lda + sc;
  const ushort* gA1 = A + (size_t)(tile_m + 128 + sr) * lda + sc;
  const ushort* gB  = B + (size_t)(tile_n + sr) * ldb + sc;

  const int fr = lane & 15;
  const int kk = (lane >> 4) * 8;

  auto stage = [&](int bb) {
    glds16(gA0, &As[bb][wave * 512]);
    glds16(gA1, &As[bb][4096 + wave * 512]);
    glds16(gB,  &Bs[bb][wave * 512]);
    gA0 += 32; gA1 += 32; gB += 32;
  };

  stage(0);
  int cur = 0;

  for (int k0 = 0; k0 < K; k0 += 32) {
    if (k0 + 32 < K) {
      stage(cur ^ 1);                                   // prefetch next tile
      asm volatile("s_waitcnt vmcnt(3)" ::: "memory");  // drain current tile only
    } else {
      asm volatile("s_waitcnt vmcnt(0)" ::: "memory");
    }
    __builtin_amdgcn_s_barrier();

    s16x8 a[4], b[4];
#pragma unroll
    for (int m = 0; m < 4; m++)
      a[m] = *(const s16x8*)&As[cur][(wr + m * 16 + fr) * 32 + kk];
#pragma unroll
    for (int n = 0; n < 4; n++)
      b[n] = *(const s16x8*)&Bs[cur][(wc + n * 16 + fr) * 32 + kk];
#pragma unroll
    for (int m = 0; m < 4; m++)
#pragma unroll
      for (int n = 0; n < 4; n++)
        acc[m][n] = __builtin_amdgcn_mfma_f32_16x16x32_bf16(a[m], b[n], acc[m][n], 0, 0, 0);

    __builtin_amdgcn_s_barrier();
    cur ^= 1;
  }

  const int rq = (lane >> 4) * 4;
#pragma unroll
  for (int m = 0; m < 4; m++)
#pragma unroll
    for (int n = 0; n < 4; n++) {
      int colg = tile_n + wc + n * 16 + fr;
      float bv = HAS_BIAS ? bias[colg] : 0.f;
#pragma unroll
      for (int r = 0; r < 4; r++) {
        int rowg = tile_m + wr + m * 16 + rq + r;
        C[(size_t)rowg * ldc + colg] = acc[m][n][r] + bv;
      }
    }
}

// ---------------- small GEMM (bounds-checked 64x64): C = A * W^T, bf16 inputs ----------------
// MODE: 0 = bf16 out
//       2 = dt-fused: sp=softplus(acc+bias[col]) -> dtf[idx]=bf16(sp),
//           dtx[idx]=bf16(sp*xcb[idx])
//       3 = f32 partial out at slice blockIdx.z (xproj split-K; stride MROWS*XPROJ_N)
template<int MODE>
__global__ __launch_bounds__(256) void k_gemm(
    const ushort* __restrict__ A, int lda,
    const ushort* __restrict__ W, int ldw,
    void* __restrict__ Cout, int ldc,
    int M, int N, int K,
    const float* __restrict__ bias,
    const bf16* __restrict__ xcb,
    bf16* __restrict__ dtxp)
{
  __shared__ ushort As[64][40];
  __shared__ ushort Ws[64][40];
  const int tile_m = blockIdx.x * 64;
  const int tile_n = blockIdx.y * 64;
  const int t = threadIdx.x;
  const int lane = t & 63;
  const int wave = t >> 6;
  const int wr = (wave >> 1) * 32;
  const int wc = (wave & 1) * 32;
  f32x4 acc[2][2] = {};

  const int kper = ((K + gridDim.z - 1) / gridDim.z + 31) & ~31;
  const int kb = blockIdx.z * kper;
  int ke = kb + kper; if (ke > K) ke = K;

  const int srow = t >> 2;
  const int scol = (t & 3) * 8;

  for (int k0 = kb; k0 < ke; k0 += 32) {
    {
      int gm = tile_m + srow, gk = k0 + scol;
      s16x8 v = {};
      if (gm < M) {
        if (gk + 8 <= K) v = *(const s16x8*)(A + (size_t)gm * lda + gk);
        else {
#pragma unroll
          for (int j = 0; j < 8; j++) if (gk + j < K) v[j] = (short)A[(size_t)gm * lda + gk + j];
        }
      }
      *(s16x8*)&As[srow][scol] = v;
    }
    {
      int gn = tile_n + srow, gk = k0 + scol;
      s16x8 v = {};
      if (gn < N) {
        if (gk + 8 <= K) v = *(const s16x8*)(W + (size_t)gn * ldw + gk);
        else {
#pragma unroll
          for (int j = 0; j < 8; j++) if (gk + j < K) v[j] = (short)W[(size_t)gn * ldw + gk + j];
        }
      }
      *(s16x8*)&Ws[srow][scol] = v;
    }
    __syncthreads();
    const int kk = (lane >> 4) * 8;
    const int fr = lane & 15;
    s16x8 a0 = *(const s16x8*)&As[wr + fr][kk];
    s16x8 a1 = *(const s16x8*)&As[wr + 16 + fr][kk];
    s16x8 b0 = *(const s16x8*)&Ws[wc + fr][kk];
    s16x8 b1 = *(const s16x8*)&Ws[wc + 16 + fr][kk];
    acc[0][0] = __builtin_amdgcn_mfma_f32_16x16x32_bf16(a0, b0, acc[0][0], 0, 0, 0);
    acc[0][1] = __builtin_amdgcn_mfma_f32_16x16x32_bf16(a0, b1, acc[0][1], 0, 0, 0);
    acc[1][0] = __builtin_amdgcn_mfma_f32_16x16x32_bf16(a1, b0, acc[1][0], 0, 0, 0);
    acc[1][1] = __builtin_amdgcn_mfma_f32_16x16x32_bf16(a1, b1, acc[1][1], 0, 0, 0);
    __syncthreads();
  }

  const int fr = lane & 15;
  const int rq = (lane >> 4) * 4;
#pragma unroll
  for (int i = 0; i < 2; i++)
#pragma unroll
    for (int j = 0; j < 2; j++) {
      int colg = tile_n + wc + j * 16 + fr;
#pragma unroll
      for (int r = 0; r < 4; r++) {
        int rowg = tile_m + wr + i * 16 + rq + r;
        if (rowg < M && colg < N) {
          float v = acc[i][j][r];
          size_t idx = (size_t)rowg * ldc + colg;
          if constexpr (MODE == 0) {
            ((bf16*)Cout)[idx] = f2b(v);
          } else if constexpr (MODE == 2) {
            v += bias[colg];
            float sp = (v > 20.f) ? v : log1pf(__expf(v));
            ((bf16*)Cout)[idx] = f2b(sp);
            dtxp[idx] = f2b(sp * b2f(xcb[idx]));
          } else {
            ((float*)Cout)[(size_t)blockIdx.z * (MROWS * XPROJ_N) + idx] = v;
          }
        }
      }
    }
}

// ---------------- causal depthwise conv (D_CONV=4) + bias + silu; 4 c/thread ----------------
__global__ __launch_bounds__(256) void k_conv(const ushort* __restrict__ xz,
    const float* __restrict__ w, const float* __restrict__ cb,
    ushort* __restrict__ xcb) {
  int id4 = blockIdx.x * 256 + threadIdx.x;         // MROWS*DINNER/4 threads
  int m = id4 / (DINNER / 4);
  int c = (id4 - m * (DINNER / 4)) * 4;
  int s = m & (SEQ_LEN - 1);
  f32x4 bias4 = *(const f32x4*)(cb + c);
  float a0 = bias4[0], a1 = bias4[1], a2 = bias4[2], a3 = bias4[3];
  f32x4 w0 = *(const f32x4*)(w + (size_t)c * 4);        // taps for c
  f32x4 w1 = *(const f32x4*)(w + (size_t)(c + 1) * 4);
  f32x4 w2 = *(const f32x4*)(w + (size_t)(c + 2) * 4);
  f32x4 w3 = *(const f32x4*)(w + (size_t)(c + 3) * 4);
#pragma unroll
  for (int k = 0; k < 4; k++) {
    int sp = s - 3 + k;
    if (sp >= 0) {
      ushort4 xv = *(const ushort4*)(xz + (size_t)(m - 3 + k) * (2 * DINNER) + c);
      a0 += w0[k] * us2f(xv.x);
      a1 += w1[k] * us2f(xv.y);
      a2 += w2[k] * us2f(xv.z);
      a3 += w3[k] * us2f(xv.w);
    }
  }
  ushort4 o;
  o.x = (ushort)f2bs(a0 / (1.f + __expf(-a0)));
  o.y = (ushort)f2bs(a1 / (1.f + __expf(-a1)));
  o.z = (ushort)f2bs(a2 / (1.f + __expf(-a2)));
  o.w = (ushort)f2bs(a3 / (1.f + __expf(-a3)));
  *(ushort4*)(xcb + (size_t)m * DINNER + c) = o;
}

// ---------------- chunked selective scan (2 kernels; chunk-combine inlined) ----------------
__global__ __launch_bounds__(256) void k_scan1(const bf16* __restrict__ dt,
    const bf16* __restrict__ dtx, const bf16* __restrict__ xdb,
    const float* __restrict__ A_log, float* __restrict__ aprod,
    float* __restrict__ hend) {
  int gid = blockIdx.x * 256 + threadIdx.x;     // SCANW*NCHUNK
  int n  = gid & 15;
  int t2 = gid >> 4;
  int j  = t2 / GROUPS;
  int cb = t2 - j * GROUPS;
  int c  = cb % DINNER;
  int b  = cb / DINNER;
  float Acn = -__expf(A_log[c * DSTATE + n]);
  float h = 0.f, ap = 1.f;
  int mbase = b * SEQ_LEN + j * CHUNK;
#pragma unroll 4
  for (int s = 0; s < CHUNK; s++) {
    int m = mbase + s;
    float dtv = b2f(dt[(size_t)m * DINNER + c]);
    float dxv = b2f(dtx[(size_t)m * DINNER + c]);
    float Bv  = b2f(xdb[(size_t)m * XPROJ_N + DTRANK + n]);
    float dA  = __expf(dtv * Acn);
    h = h * dA + dxv * Bv;
    ap *= dA;
  }
  aprod[gid] = ap;
  hend[gid]  = h;
}

// scan3: inlines the former k_scan2 chunk-combine (j is block-uniform since
// SCANW % (256/16) aligned; identical arithmetic order -> bitwise-equal h),
// then the per-chunk re-scan with fused ycomb tail. aprod/hend are 6MB total
// (L2/L3-resident) so the O(j) redundant loads are ~free; removes k_scan2
// dispatches and the hin round-trip.
__global__ __launch_bounds__(256) void k_scan3(const bf16* __restrict__ dt,
    const bf16* __restrict__ dtx, const bf16* __restrict__ xdb,
    const float* __restrict__ A_log,
    const float* __restrict__ aprod, const float* __restrict__ hend,
    const bf16* __restrict__ xcb, const bf16* __restrict__ xz,
    const float* __restrict__ D_ssm, bf16* __restrict__ ybf) {
  __shared__ float p_lds[16][CHUNK + 1];        // +1 pad: conflict-free writes
  int gid = blockIdx.x * 256 + threadIdx.x;     // SCANW*NCHUNK
  int n  = gid & 15;
  int g  = (threadIdx.x >> 4) & 15;             // group within block
  int t2 = gid >> 4;
  int j  = t2 / GROUPS;                         // uniform within block
  int cb = t2 - j * GROUPS;
  int c  = cb % DINNER;
  int b  = cb / DINNER;
  float Acn = -__expf(A_log[c * DSTATE + n]);

  // inline chunk-combine (== former k_scan2 up to chunk j, same order)
  float h = 0.f;
  {
    size_t base = (size_t)cb * 16 + n;          // idx within one chunk slab
    for (int jj = 0; jj < j; jj++) {
      size_t o = (size_t)jj * SCANW + base;
      h = aprod[o] * h + hend[o];
    }
  }

  int mbase = b * SEQ_LEN + j * CHUNK;
#pragma unroll 2
  for (int s = 0; s < CHUNK; s++) {
    int m = mbase + s;
    float dtv = b2f(dt[(size_t)m * DINNER + c]);
    float dxv = b2f(dtx[(size_t)m * DINNER + c]);
    float Bv  = b2f(xdb[(size_t)m * XPROJ_N + DTRANK + n]);
    float Cv  = b2f(xdb[(size_t)m * XPROJ_N + DTRANK + DSTATE + n]);
    float dA  = __expf(dtv * Acn);
    h = h * dA + dxv * Bv;
    float p = h * Cv;
    p += __shfl_xor(p, 8);
    p += __shfl_xor(p, 4);
    p += __shfl_xor(p, 2);
    p += __shfl_xor(p, 1);
    if (n == 0) p_lds[g][s] = p;
  }
  __syncthreads();
  int c0 = c - g;                               // first c of this block
#pragma unroll
  for (int i = 0; i < 4; i++) {
    int idx = threadIdx.x + i * 256;
    int g2 = idx & 15;
    int ml = idx >> 4;
    int m  = mbase + ml;
    int cc = c0 + g2;
    float yv  = p_lds[g2][ml];
    float z   = b2f(xz[(size_t)m * (2 * DINNER) + DINNER + cc]);
    float sil = z / (1.f + __expf(-z));
    float v = (yv + D_ssm[cc] * b2f(xcb[(size_t)m * DINNER + cc])) * sil;
    ybf[(size_t)m * DINNER + cc] = f2b(v);
  }
}

extern "C" void kernel_launch(void* const* d_in, const int* in_sizes, int n_in,
                              void* d_out, int out_size, void* d_ws, size_t ws_size,
                              hipStream_t stream) {
  const int*   tokens    = (const int*)  d_in[0];
  const float* embedding = (const float*)d_in[1];
  const float* head_bias = (const float*)d_in[2];
  const float* ln_g      = (const float*)d_in[3];
  const float* ln_b      = (const float*)d_in[4];
  const float* W_in      = (const float*)d_in[5];
  const float* conv_w    = (const float*)d_in[6];
  const float* conv_b    = (const float*)d_in[7];
  const float* W_xproj   = (const float*)d_in[8];
  const float* W_dt      = (const float*)d_in[9];
  const float* b_dt      = (const float*)d_in[10];
  const float* A_log     = (const float*)d_in[11];
  const float* D_ssm     = (const float*)d_in[12];
  const float* W_out     = (const float*)d_in[13];
  const float* norm_g    = (const float*)d_in[14];
  const float* norm_b    = (const float*)d_in[15];
  float* out = (float*)d_out;

  char* ws = (char*)d_ws;
  size_t off = 0;
  auto alloc = [&](size_t bytes) -> char* {
    char* p = ws + off;
    off = (off + bytes + 255) & ~(size_t)255;
    return p;
  };
  float*  x     = (float*) alloc((size_t)MROWS * DMODEL * 4);
  bf16*   xln   = (bf16*)  alloc((size_t)MROWS * DMODEL * 2);
  bf16*   xz    = (bf16*)  alloc((size_t)MROWS * 2 * DINNER * 2);
  bf16*   xcb   = (bf16*)  alloc((size_t)MROWS * DINNER * 2);
  bf16*   xdb   = (bf16*)  alloc((size_t)MROWS * XPROJ_N * 2);
  float*  xdbp  = (float*) alloc((size_t)XSPLIT * MROWS * XPROJ_N * 4);
  bf16*   dtf   = (bf16*)  alloc((size_t)MROWS * DINNER * 2);
  bf16*   dtx   = (bf16*)  alloc((size_t)MROWS * DINNER * 2);
  bf16*   ybf   = (bf16*)  alloc((size_t)MROWS * DINNER * 2);
  float*  aprod = (float*) alloc((size_t)SCANW * NCHUNK * 4);
  float*  hend  = (float*) alloc((size_t)SCANW * NCHUNK * 4);
  float*  wpart = (float*) alloc((size_t)WSPLIT * MROWS * DMODEL * 4);
  ushort* ebf   = (ushort*)alloc((size_t)NVOCAB * DMODEL * 2);
  ushort* winb  = (ushort*)alloc((size_t)NLAYERS * 2 * DINNER * DMODEL * 2);
  ushort* wxpb  = (ushort*)alloc((size_t)NLAYERS * XPROJ_N * DINNER * 2);
  ushort* wdtb  = (ushort*)alloc((size_t)NLAYERS * DINNER * DTRANK * 2);
  ushort* woutb = (ushort*)alloc((size_t)NLAYERS * DMODEL * DINNER * 2);
  (void)ws_size; (void)in_sizes; (void)n_in; (void)out_size;

  // all weight conversions f32 -> bf16 in ONE dispatch
  k_cvt5<<<(CVT_E4 + 255) / 256, 256, 0, stream>>>(
      embedding, W_in, W_out, W_xproj, W_dt,
      ebf, winb, woutb, wxpb, wdtb);

  // fused embedding gather + layer-0 LN
  k_embed_ln<<<MROWS, 256, 0, stream>>>(tokens, embedding, x, xln, ln_g, ln_b);

  const int XDBN4 = MROWS * XPROJ_N / 4;          // 40960

  for (int L = 0; L < NLAYERS; L++) {
    // W_in GEMM -> bf16 xz (OMODE=2)
    k_gemm128<false, 2><<<dim3(MROWS / 128, (2 * DINNER) / 128), 512, 0, stream>>>(
        (const ushort*)xln, DMODEL,
        winb + (size_t)L * 2 * DINNER * DMODEL, DMODEL,
        (void*)xz, 2 * DINNER, nullptr, MROWS, 2 * DINNER, DMODEL);

    k_conv<<<MROWS * DINNER / 1024, 256, 0, stream>>>(
        (const ushort*)xz, conv_w + (size_t)L * DINNER * 4,
        conv_b + (size_t)L * DINNER, (ushort*)xcb);

    // xproj GEMM: split-K=8 into per-z f32 partial slices (no atomics), then sum->bf16
    k_gemm<3><<<dim3(MROWS / 64, 2, XSPLIT), 256, 0, stream>>>(
        (const ushort*)xcb, DINNER,
        wxpb + (size_t)L * XPROJ_N * DINNER, DINNER,
        (void*)xdbp, XPROJ_N, MROWS, XPROJ_N, DINNER,
        nullptr, nullptr, nullptr);
    k_xsum<<<(XDBN4 + 255) / 256, 256, 0, stream>>>(xdbp, (ushort*)xdb, XDBN4);

    // dt GEMM with fused softplus(+b_dt): dtf = bf16(sp), dtx = bf16(sp*xc)
    k_gemm<2><<<dim3(MROWS / 64, DINNER / 64), 256, 0, stream>>>(
        (const ushort*)xdb, XPROJ_N,
        wdtb + (size_t)L * DINNER * DTRANK, DTRANK,
        (void*)dtf, DINNER, MROWS, DINNER, DTRANK,
        b_dt + (size_t)L * DINNER, xcb, dtx);

    const float* Al = A_log + (size_t)L * DINNER * DSTATE;
    k_scan1<<<SCANW * NCHUNK / 256, 256, 0, stream>>>(dtf, dtx, xdb, Al, aprod, hend);
    // scan3 with inlined chunk-combine (no k_scan2, no hin buffer)
    k_scan3<<<SCANW * NCHUNK / 256, 256, 0, stream>>>(
        dtf, dtx, xdb, Al, aprod, hend, xcb, xz, D_ssm + (size_t)L * DINNER, ybf);

    // W_out GEMM: split-K=4 into f32 partials (plain stores, no atomics)
    k_gemm128<false, 3><<<dim3(MROWS / 128, DMODEL / 128, WSPLIT), 512, 0, stream>>>(
        (const ushort*)ybf, DINNER,
        woutb + (size_t)L * DMODEL * DINNER, DINNER,
        (void*)wpart, DMODEL, nullptr, MROWS, DMODEL, DINNER);

    // residual-add + LN (next layer's gamma/beta, or final norm after last layer)
    const float* gg = (L < NLAYERS - 1) ? ln_g + (L + 1) * DMODEL : norm_g;
    const float* bb = (L < NLAYERS - 1) ? ln_b + (L + 1) * DMODEL : norm_b;
    k_lnadd<<<MROWS, 256, 0, stream>>>(x, wpart, xln, gg, bb);
  }

  // LM head: 256x128-tile BK=32 GEMM (2048 x 32000 x 768), f32 out + bias
  k_gemmhead<true><<<dim3(MROWS / 256, NVOCAB / 128), 512, 0, stream>>>(
      (const ushort*)xln, DMODEL,
      ebf, DMODEL,
      out, NVOCAB, head_bias, MROWS, NVOCAB, DMODEL);
}